// Round 10
// baseline (851.819 us; speedup 1.0000x reference)
//
#include <hip/hip_runtime.h>

#define NN 100000
#define NE 3200000
#define NIN 16
#define ECH 16
#define F 10
#define FP 16          // padded node row stride = 64 B
#define OC 32
#define CSB 104        // colsum stage-1 blocks
#define CSH 10         // coarse shift: 1024 nodes per bucket
#define CBN 1024
#define NCB 98         // ceil(NN/1024)
#define CHA 4096       // edges per passA block
#define CSZ 8192       // edges per reduce chunk
#define MAXC 5         // chunks per bucket (max bucket ~33.5K < 40960)

__device__ __forceinline__ unsigned pk_bf16(float a, float b) {
    unsigned ua = __float_as_uint(a); ua = (ua + 0x7FFFu + ((ua >> 16) & 1u)) >> 16;
    unsigned ub = __float_as_uint(b); ub = (ub + 0x7FFFu + ((ub >> 16) & 1u)) >> 16;
    return ua | (ub << 16);
}
__device__ __forceinline__ float bf_lo(unsigned u) { return __uint_as_float(u << 16); }
__device__ __forceinline__ float bf_hi(unsigned u) { return __uint_as_float(u & 0xFFFF0000u); }

// ---------- coarse histogram (98 buckets, LDS)
__global__ __launch_bounds__(256) void k_chist(const int* __restrict__ dst,
                                               int* __restrict__ ccnt)
{
    __shared__ int lcnt[NCB];
    int t = threadIdx.x;
    if (t < NCB) lcnt[t] = 0;
    __syncthreads();
    for (int e = blockIdx.x * 256 + t; e < NE; e += gridDim.x * 256)
        atomicAdd(&lcnt[dst[e] >> CSH], 1);
    __syncthreads();
    if (t < NCB) {
        int v = lcnt[t];
        if (v) atomicAdd(&ccnt[t], v);
    }
}

// ---------- scan of 98 coarse counts (128 threads)
__global__ void k_cscan(const int* __restrict__ ccnt, int* __restrict__ cbase)
{
    __shared__ int w0tot;
    int t = threadIdx.x;
    int v = (t < NCB) ? ccnt[t] : 0;
    int lane = t & 63, w = t >> 6;
    int inc = v;
    for (int d = 1; d < 64; d <<= 1) { int u = __shfl_up(inc, d); if (lane >= d) inc += u; }
    if (w == 0 && lane == 63) w0tot = inc;
    __syncthreads();
    int excl = inc - v + (w == 1 ? w0tot : 0);
    if (t < NCB) cbase[t] = excl;
    if (t == 0) cbase[NCB] = NE;
}

// ---------- passA: stream ea coalesced, project, scatter 24B payload to coarse-bucket runs
// pv0[pos] = {bf16 ev[0..7]}   pv1[pos] = {bf16 ev[8..9], src | dlocal<<17}
__global__ __launch_bounds__(256) void k_passA(
    const int* __restrict__ src, const int* __restrict__ dst,
    const float* __restrict__ ea,
    const int* __restrict__ cbase, int* __restrict__ cur,
    const float* __restrict__ W4, const float* __restrict__ b4,
    uint4* __restrict__ pv0, uint2* __restrict__ pv1)
{
    __shared__ int lcnt[NCB];
    __shared__ int lbb[NCB];
    __shared__ float w4[ECH*F], b4s[F];
    int t = threadIdx.x;
    if (t < ECH*F) w4[t] = W4[t];
    if (t < F) b4s[t] = b4[t];
    if (t < NCB) lcnt[t] = 0;
    int e0 = blockIdx.x * CHA;
    int e1 = e0 + CHA; if (e1 > NE) e1 = NE;
    __syncthreads();
    for (int e = e0 + t; e < e1; e += 256)
        atomicAdd(&lcnt[dst[e] >> CSH], 1);
    __syncthreads();
    if (t < NCB) {
        int c = lcnt[t];
        lbb[t] = c ? (cbase[t] + atomicAdd(&cur[t], c)) : 0;
        lcnt[t] = 0;                     // reuse as local cursor
    }
    __syncthreads();
    for (int e = e0 + t; e < e1; e += 256) {
        int d = dst[e];
        int cb = d >> CSH;
        const float4* q = (const float4*)(ea + (size_t)e * ECH);
        float4 a0 = q[0], a1 = q[1], a2 = q[2], a3 = q[3];
        float av[ECH] = {a0.x,a0.y,a0.z,a0.w, a1.x,a1.y,a1.z,a1.w,
                         a2.x,a2.y,a2.z,a2.w, a3.x,a3.y,a3.z,a3.w};
        float ev[F];
#pragma unroll
        for (int j = 0; j < F; ++j) ev[j] = b4s[j];
#pragma unroll
        for (int i = 0; i < ECH; ++i) {
            float ai = av[i];
#pragma unroll
            for (int j = 0; j < F; ++j) ev[j] = fmaf(ai, w4[i*F + j], ev[j]);
        }
#pragma unroll
        for (int j = 0; j < F; ++j) ev[j] = fmaxf(ev[j], 0.f);
        int idx = atomicAdd(&lcnt[cb], 1);
        int pos = lbb[cb] + idx;
        pv0[pos] = make_uint4(pk_bf16(ev[0],ev[1]), pk_bf16(ev[2],ev[3]),
                              pk_bf16(ev[4],ev[5]), pk_bf16(ev[6],ev[7]));
        pv1[pos] = make_uint2(pk_bf16(ev[8],ev[9]),
                              (unsigned)src[e] | ((unsigned)(d & (CBN-1)) << 17));
    }
}

// ---------- passB: coalesced payload read, LDS table accumulate, flush partials
__global__ __launch_bounds__(256) void k_passB(
    const uint4* __restrict__ pv0, const uint2* __restrict__ pv1,
    const int* __restrict__ cbase, float* __restrict__ partial)
{
    __shared__ float agg[CBN * F];     // 40 KB
    int t = threadIdx.x;
    for (int i = t; i < CBN*F; i += 256) agg[i] = 0.f;
    __syncthreads();
    int c = blockIdx.x / MAXC, ch = blockIdx.x % MAXC;
    int bas = cbase[c], end = cbase[c + 1];
    int st = bas + ch * CSZ;
    int en = st + CSZ; if (en > end) en = end;
    for (int i = st + t; i < en; i += 256) {
        uint4 h0 = pv0[i];
        uint2 h1 = pv1[i];
        int dl = (h1.y >> 17) & (CBN - 1);
        float* row = &agg[dl * F];
        atomicAdd(row + 0, bf_lo(h0.x)); atomicAdd(row + 1, bf_hi(h0.x));
        atomicAdd(row + 2, bf_lo(h0.y)); atomicAdd(row + 3, bf_hi(h0.y));
        atomicAdd(row + 4, bf_lo(h0.z)); atomicAdd(row + 5, bf_hi(h0.z));
        atomicAdd(row + 6, bf_lo(h0.w)); atomicAdd(row + 7, bf_hi(h0.w));
        atomicAdd(row + 8, bf_lo(h1.x)); atomicAdd(row + 9, bf_hi(h1.x));
    }
    __syncthreads();
    float* pp = partial + (size_t)blockIdx.x * (CBN * F);
    for (int i = t; i < CBN*F; i += 256) pp[i] = agg[i];
}

// ---------- finA: sum partials + x@W1 + agg@W3 + bias -> base, fbA(bf16)
__global__ __launch_bounds__(256) void k_finA(
    const float* __restrict__ x, const float* __restrict__ partial,
    const float* __restrict__ W1, const float* __restrict__ b1,
    const float* __restrict__ b2,
    const float* __restrict__ W3, const float* __restrict__ b3,
    float* __restrict__ base, unsigned* __restrict__ fb)
{
    __shared__ float w1[NIN*F], w3s[F*F], bb[F];
    int t = threadIdx.x;
    if (t < NIN*F) w1[t] = W1[t];
    if (t < F*F)   w3s[t] = W3[t];
    if (t < F) bb[t] = b1[t] + b2[t] + b3[t];
    __syncthreads();
    int n = blockIdx.x * 256 + t;
    if (n >= NN) return;
    int c = n >> CSH, dl = n & (CBN - 1);
    float a[F];
#pragma unroll
    for (int j = 0; j < F; ++j) a[j] = 0.f;
    for (int ch = 0; ch < MAXC; ++ch) {
        const float* pp = partial + (size_t)(c * MAXC + ch) * (CBN * F) + dl * F;
#pragma unroll
        for (int j = 0; j < F; ++j) a[j] += pp[j];
    }
    const float4* px = (const float4*)(x + (size_t)n * NIN);
    float4 x0 = px[0], x1 = px[1], x2 = px[2], x3 = px[3];
    float xv[NIN] = {x0.x,x0.y,x0.z,x0.w, x1.x,x1.y,x1.z,x1.w,
                     x2.x,x2.y,x2.z,x2.w, x3.x,x3.y,x3.z,x3.w};
    float acc[F];
#pragma unroll
    for (int j = 0; j < F; ++j) acc[j] = bb[j];
#pragma unroll
    for (int i = 0; i < NIN; ++i) {
        float xi = xv[i];
#pragma unroll
        for (int j = 0; j < F; ++j) acc[j] = fmaf(xi, w1[i*F + j], acc[j]);
    }
#pragma unroll
    for (int i = 0; i < F; ++i) {
        float ai = a[i];
#pragma unroll
        for (int j = 0; j < F; ++j) acc[j] = fmaf(ai, w3s[i*F + j], acc[j]);
    }
    float4* pb = (float4*)(base + (size_t)n * FP);
    pb[0] = make_float4(acc[0], acc[1], acc[2], acc[3]);
    pb[1] = make_float4(acc[4], acc[5], acc[6], acc[7]);
    pb[2] = make_float4(acc[8], acc[9], 0.f, 0.f);
    pb[3] = make_float4(0.f, 0.f, 0.f, 0.f);
    float fv[F];
#pragma unroll
    for (int j = 0; j < F; ++j) fv[j] = fmaxf(acc[j], 0.f);
    uint4* pf = (uint4*)(fb + (size_t)n * 8);
    pf[0] = make_uint4(pk_bf16(fv[0],fv[1]), pk_bf16(fv[2],fv[3]),
                       pk_bf16(fv[4],fv[5]), pk_bf16(fv[6],fv[7]));
    pf[1] = make_uint4(pk_bf16(fv[8],fv[9]), 0u, 0u, 0u);
}

// ---------- iterC: coalesced pv1 read, gather fb[src] (L2), LDS table, flush partials
__global__ __launch_bounds__(256) void k_iterC(
    const uint2* __restrict__ pv1, const int* __restrict__ cbase,
    const unsigned* __restrict__ fbO, float* __restrict__ partial)
{
    __shared__ float agg[CBN * F];     // 40 KB
    int t = threadIdx.x;
    for (int i = t; i < CBN*F; i += 256) agg[i] = 0.f;
    __syncthreads();
    int c = blockIdx.x / MAXC, ch = blockIdx.x % MAXC;
    int bas = cbase[c], end = cbase[c + 1];
    int st = bas + ch * CSZ;
    int en = st + CSZ; if (en > end) en = end;
    for (int i = st + t; i < en; i += 256) {
        unsigned sdv = pv1[i].y;
        int s = sdv & 0x1FFFF;
        int dl = (sdv >> 17) & (CBN - 1);
        const unsigned* r = fbO + (size_t)s * 8;
        uint2 q0 = *(const uint2*)r;
        uint2 q1 = *(const uint2*)(r + 2);
        unsigned q4 = r[4];
        float* row = &agg[dl * F];
        atomicAdd(row + 0, bf_lo(q0.x)); atomicAdd(row + 1, bf_hi(q0.x));
        atomicAdd(row + 2, bf_lo(q0.y)); atomicAdd(row + 3, bf_hi(q0.y));
        atomicAdd(row + 4, bf_lo(q1.x)); atomicAdd(row + 5, bf_hi(q1.x));
        atomicAdd(row + 6, bf_lo(q1.y)); atomicAdd(row + 7, bf_hi(q1.y));
        atomicAdd(row + 8, bf_lo(q4));   atomicAdd(row + 9, bf_hi(q4));
    }
    __syncthreads();
    float* pp = partial + (size_t)blockIdx.x * (CBN * F);
    for (int i = t; i < CBN*F; i += 256) pp[i] = agg[i];
}

// ---------- iterfin: featN = relu(base + (partialsum + self) @ W2) -> fb and/or f32
__global__ __launch_bounds__(256) void k_iterfin(
    const float* __restrict__ partial, const unsigned* __restrict__ fbO,
    const float* __restrict__ base, const float* __restrict__ W2,
    unsigned* __restrict__ fbN, float* __restrict__ featN,
    int wfb, int wf32)
{
    __shared__ float w2[F*F];
    int t = threadIdx.x;
    if (t < F*F) w2[t] = W2[t];
    __syncthreads();
    int n = blockIdx.x * 256 + t;
    if (n >= NN) return;
    int c = n >> CSH, dl = n & (CBN - 1);
    float a[F];
#pragma unroll
    for (int j = 0; j < F; ++j) a[j] = 0.f;
    for (int ch = 0; ch < MAXC; ++ch) {
        const float* pp = partial + (size_t)(c * MAXC + ch) * (CBN * F) + dl * F;
#pragma unroll
        for (int j = 0; j < F; ++j) a[j] += pp[j];
    }
    const unsigned* r = fbO + (size_t)n * 8;   // self row
    uint2 q0 = *(const uint2*)r;
    uint2 q1 = *(const uint2*)(r + 2);
    unsigned q4 = r[4];
    a[0] += bf_lo(q0.x); a[1] += bf_hi(q0.x);
    a[2] += bf_lo(q0.y); a[3] += bf_hi(q0.y);
    a[4] += bf_lo(q1.x); a[5] += bf_hi(q1.x);
    a[6] += bf_lo(q1.y); a[7] += bf_hi(q1.y);
    a[8] += bf_lo(q4);   a[9] += bf_hi(q4);
    const float4* pb = (const float4*)(base + (size_t)n * FP);
    float4 c0 = pb[0], c1 = pb[1], c2 = pb[2];
    float acc[F] = {c0.x,c0.y,c0.z,c0.w, c1.x,c1.y,c1.z,c1.w, c2.x,c2.y};
#pragma unroll
    for (int i = 0; i < F; ++i) {
        float ai = a[i];
#pragma unroll
        for (int j = 0; j < F; ++j) acc[j] = fmaf(ai, w2[i*F + j], acc[j]);
    }
    float fv[F];
#pragma unroll
    for (int j = 0; j < F; ++j) fv[j] = fmaxf(acc[j], 0.f);
    if (wfb) {
        uint4* pf = (uint4*)(fbN + (size_t)n * 8);
        pf[0] = make_uint4(pk_bf16(fv[0],fv[1]), pk_bf16(fv[2],fv[3]),
                           pk_bf16(fv[4],fv[5]), pk_bf16(fv[6],fv[7]));
        pf[1] = make_uint4(pk_bf16(fv[8],fv[9]), 0u, 0u, 0u);
    }
    if (wf32) {
        float4* pf = (float4*)(featN + (size_t)n * FP);
        pf[0] = make_float4(fv[0], fv[1], fv[2], fv[3]);
        pf[1] = make_float4(fv[4], fv[5], fv[6], fv[7]);
        pf[2] = make_float4(fv[8], fv[9], 0.f, 0.f);
        pf[3] = make_float4(0.f, 0.f, 0.f, 0.f);
    }
}

// ---------- colsum stage 1
__global__ __launch_bounds__(256) void k_colsum(
    const float* __restrict__ feat, float* __restrict__ cpart)
{
    __shared__ float sm[4][F];
    int t = threadIdx.x;
    float v[F];
#pragma unroll
    for (int j = 0; j < F; ++j) v[j] = 0.f;
    for (int n = blockIdx.x * 256 + t; n < NN; n += CSB * 256) {
        const float4* p = (const float4*)(feat + (size_t)n * FP);
        float4 v0 = p[0], v1 = p[1], v2 = p[2];
        v[0]+=v0.x; v[1]+=v0.y; v[2]+=v0.z; v[3]+=v0.w;
        v[4]+=v1.x; v[5]+=v1.y; v[6]+=v1.z; v[7]+=v1.w;
        v[8]+=v2.x; v[9]+=v2.y;
    }
#pragma unroll
    for (int off = 32; off > 0; off >>= 1) {
#pragma unroll
        for (int j = 0; j < F; ++j) v[j] += __shfl_down(v[j], off);
    }
    int wid = t >> 6;
    if ((t & 63) == 0) {
#pragma unroll
        for (int j = 0; j < F; ++j) sm[wid][j] = v[j];
    }
    __syncthreads();
    if (t < F) {
        float s = sm[0][t] + sm[1][t] + sm[2][t] + sm[3][t];
        cpart[blockIdx.x * F + t] = s;
    }
}

// ---------- tiny global-term finisher
__global__ void k_gsmall(
    const float* __restrict__ cpart, const float* __restrict__ W6,
    const float* __restrict__ b6, const float* __restrict__ W5,
    const float* __restrict__ b5, float* __restrict__ gpart)
{
    __shared__ float gcol[F], r1[F];
    int t = threadIdx.x;
    if (t < F) {
        float s = 0.f;
        for (int b = 0; b < CSB; ++b) s += cpart[b * F + t];
        gcol[t] = s;
    }
    __syncthreads();
    if (t < F) {
        float acc = b6[t];
        for (int i = 0; i < F; ++i) acc = fmaf(gcol[i], W6[i*F + t], acc);
        r1[t] = acc > 0.f ? acc : 0.f;
    }
    __syncthreads();
    if (t < OC) {
        float acc = b5[t];
        for (int i = 0; i < F; ++i) acc = fmaf(r1[i], W5[i*OC + t], acc);
        gpart[t] = acc;
    }
}

// ---------- output
__global__ __launch_bounds__(256) void k_out(
    const float* __restrict__ feat, const float* __restrict__ W7,
    const float* __restrict__ b7, const float* __restrict__ W5,
    const float* __restrict__ gpart, float* __restrict__ out)
{
    __shared__ float w7[F*F], bb7[F], w5[F*OC], gp[OC];
    int t = threadIdx.x;
    if (t < F*F) w7[t] = W7[t];
    if (t < F) bb7[t] = b7[t];
    for (int i = t; i < F*OC; i += 256) w5[i] = W5[F*OC + i];
    if (t < OC) gp[t] = gpart[t];
    __syncthreads();
    int n = blockIdx.x * 256 + t;
    if (n >= NN) return;
    const float4* p = (const float4*)(feat + (size_t)n * FP);
    float4 v0 = p[0], v1 = p[1], v2 = p[2];
    float f[F] = {v0.x,v0.y,v0.z,v0.w, v1.x,v1.y,v1.z,v1.w, v2.x,v2.y};
    float h[F];
#pragma unroll
    for (int j = 0; j < F; ++j) h[j] = bb7[j];
#pragma unroll
    for (int i = 0; i < F; ++i) {
        float fi = f[i];
#pragma unroll
        for (int j = 0; j < F; ++j) h[j] = fmaf(fi, w7[i*F + j], h[j]);
    }
#pragma unroll
    for (int j = 0; j < F; ++j) h[j] = h[j] > 0.f ? h[j] : 0.f;
    float o[OC];
#pragma unroll
    for (int k = 0; k < OC; ++k) o[k] = gp[k];
#pragma unroll
    for (int j = 0; j < F; ++j) {
        float hj = h[j];
#pragma unroll
        for (int k = 0; k < OC; ++k) o[k] = fmaf(hj, w5[j*OC + k], o[k]);
    }
    float4* po = (float4*)(out + (size_t)n * OC);
#pragma unroll
    for (int k = 0; k < 8; ++k)
        po[k] = make_float4(o[4*k], o[4*k+1], o[4*k+2], o[4*k+3]);
}

extern "C" void kernel_launch(void* const* d_in, const int* in_sizes, int n_in,
                              void* d_out, int out_size, void* d_ws, size_t ws_size,
                              hipStream_t stream)
{
    const float* x   = (const float*)d_in[0];
    const int*   ei  = (const int*)d_in[1];
    const float* ea  = (const float*)d_in[2];
    const float* W1  = (const float*)d_in[3];
    const float* b1  = (const float*)d_in[4];
    const float* W2  = (const float*)d_in[5];
    const float* b2  = (const float*)d_in[6];
    const float* W3  = (const float*)d_in[7];
    const float* b3  = (const float*)d_in[8];
    const float* W4  = (const float*)d_in[9];
    const float* b4  = (const float*)d_in[10];
    const float* W5  = (const float*)d_in[11];
    const float* b5  = (const float*)d_in[12];
    const float* W6  = (const float*)d_in[13];
    const float* b6  = (const float*)d_in[14];
    const float* W7  = (const float*)d_in[15];
    const float* b7  = (const float*)d_in[16];

    const int* src = ei;            // edge_index[0]
    const int* dst = ei + NE;       // edge_index[1]

    // workspace layout (16B-aligned chunks)
    char* w = (char*)d_ws;
    uint4* pv0    = (uint4*)w;                 w += (size_t)NE * 16;               // 51.2 MB
    uint2* pv1    = (uint2*)w;                 w += (size_t)NE * 8;                // 25.6 MB
    float* partial = (float*)w;                w += (size_t)NCB * MAXC * CBN * F * 4; // 19.6 MB
    float* base   = (float*)w;                 w += (size_t)NN * FP * 4;           // 6.4 MB
    float* featA  = (float*)w;                 w += (size_t)NN * FP * 4;
    unsigned* fbA = (unsigned*)w;              w += (size_t)NN * 32;               // 3.2 MB
    unsigned* fbB = (unsigned*)w;              w += (size_t)NN * 32;
    int* ccnt     = (int*)w;                   w += (size_t)NCB * 4;               // zeroed
    int* cur      = (int*)w;                   w += (size_t)NCB * 4;               // zeroed (contiguous)
    int* cbase    = (int*)w;                   w += (size_t)(NCB + 16) * 4;
    float* cpart  = (float*)w;                 w += (size_t)CSB * F * 4;
    float* gpart  = (float*)w;                 w += 32 * 4;

    const int NB = (NN + 255) / 256;           // 391
    const int PA = (NE + CHA - 1) / CHA;       // 782
    const int RB = NCB * MAXC;                 // 490

    hipMemsetAsync(ccnt, 0, (size_t)2 * NCB * 4, stream);   // ccnt + cur

    k_chist  <<<512, 256, 0, stream>>>(dst, ccnt);
    k_cscan  <<<1, 128, 0, stream>>>(ccnt, cbase);
    k_passA  <<<PA, 256, 0, stream>>>(src, dst, ea, cbase, cur, W4, b4, pv0, pv1);
    k_passB  <<<RB, 256, 0, stream>>>(pv0, pv1, cbase, partial);
    k_finA   <<<NB, 256, 0, stream>>>(x, partial, W1, b1, b2, W3, b3, base, fbA);

    k_iterC  <<<RB, 256, 0, stream>>>(pv1, cbase, fbA, partial);
    k_iterfin<<<NB, 256, 0, stream>>>(partial, fbA, base, W2, fbB, (float*)nullptr, 1, 0);
    k_iterC  <<<RB, 256, 0, stream>>>(pv1, cbase, fbB, partial);
    k_iterfin<<<NB, 256, 0, stream>>>(partial, fbB, base, W2, (unsigned*)nullptr, featA, 0, 1);

    k_colsum <<<CSB, 256, 0, stream>>>(featA, cpart);
    k_gsmall <<<1, 64, 0, stream>>>(cpart, W6, b6, W5, b5, gpart);
    k_out    <<<NB, 256, 0, stream>>>(featA, W7, b7, W5, gpart, (float*)d_out);
}

// Round 11
// 835.714 us; speedup vs baseline: 1.0193x; 1.0193x over previous
//
#include <hip/hip_runtime.h>

#define NN 100000
#define NE 3200000
#define NIN 16
#define ECH 16
#define F 10
#define FP 16          // padded node row stride = 64 B (final f32 feat only)
#define OC 32
#define CSB 104        // colsum stage-1 blocks
#define BKSH 7         // 128 nodes per bucket
#define NBK 782        // ceil(NN / 128)
#define CH 8192        // edges per binscat block

__device__ __forceinline__ unsigned pk_bf16(float a, float b) {
    unsigned ua = __float_as_uint(a); ua = (ua + 0x7FFFu + ((ua >> 16) & 1u)) >> 16;
    unsigned ub = __float_as_uint(b); ub = (ub + 0x7FFFu + ((ub >> 16) & 1u)) >> 16;
    return ua | (ub << 16);
}
__device__ __forceinline__ float bf_lo(unsigned u) { return __uint_as_float(u << 16); }
__device__ __forceinline__ float bf_hi(unsigned u) { return __uint_as_float(u & 0xFFFF0000u); }

// ---------- bucket histogram
__global__ __launch_bounds__(256) void k_binhist(const int* __restrict__ dst,
                                                 int* __restrict__ bkcnt)
{
    __shared__ int lcnt[NBK];
    int t = threadIdx.x;
    for (int k = t; k < NBK; k += 256) lcnt[k] = 0;
    __syncthreads();
    for (int e = blockIdx.x * 256 + t; e < NE; e += gridDim.x * 256)
        atomicAdd(&lcnt[dst[e] >> BKSH], 1);
    __syncthreads();
    for (int k = t; k < NBK; k += 256) {
        int v = lcnt[k];
        if (v) atomicAdd(&bkcnt[k], v);
    }
}

// ---------- scan of bucket counts (NBK=782 <= 1024)
__global__ __launch_bounds__(1024) void k_bkscan(const int* __restrict__ bkcnt,
                                                 int* __restrict__ bkbase)
{
    __shared__ int wsum[16], wscan[16];
    int t = threadIdx.x;
    int v = (t < NBK) ? bkcnt[t] : 0;
    int lane = t & 63, w = t >> 6;
    int inc = v;
    for (int d = 1; d < 64; d <<= 1) { int u = __shfl_up(inc, d); if (lane >= d) inc += u; }
    if (lane == 63) wsum[w] = inc;
    __syncthreads();
    if (t < 16) {
        int u = wsum[t];
        for (int d = 1; d < 16; d <<= 1) { int x2 = __shfl_up(u, d); if (t >= d) u += x2; }
        wscan[t] = u;
    }
    __syncthreads();
    int excl = inc - v + (w > 0 ? wscan[w - 1] : 0);
    if (t < NBK) bkbase[t] = excl;
    if (t == 0) bkbase[NBK] = NE;
}

// ---------- bin scatter: one 8B int2 {src, dlocal<<22|eid} per edge into bucket runs
__global__ __launch_bounds__(256) void k_binscat(
    const int* __restrict__ src, const int* __restrict__ dst,
    const int* __restrict__ bkbase, int* __restrict__ cur,
    int2* __restrict__ pair)
{
    __shared__ int lcnt[NBK];
    __shared__ int lbb[NBK];
    int t = threadIdx.x;
    int e0 = blockIdx.x * CH;
    int e1 = e0 + CH; if (e1 > NE) e1 = NE;
    for (int k = t; k < NBK; k += 256) lcnt[k] = 0;
    __syncthreads();
    for (int e = e0 + t; e < e1; e += 256)
        atomicAdd(&lcnt[dst[e] >> BKSH], 1);
    __syncthreads();
    for (int k = t; k < NBK; k += 256) {
        int c = lcnt[k];
        lbb[k] = c ? (bkbase[k] + atomicAdd(&cur[k], c)) : 0;
        lcnt[k] = 0;
    }
    __syncthreads();
    for (int e = e0 + t; e < e1; e += 256) {
        int d = dst[e];
        int bk = d >> BKSH;
        int idx = atomicAdd(&lcnt[bk], 1);
        pair[lbb[bk] + idx] = make_int2(src[e], ((d & 127) << 22) | e);
    }
}

// ---------- init: block per bucket, 4 lanes/edge ea gather, LDS table, fused finish
__global__ __launch_bounds__(256) void k_initB(
    const float* __restrict__ x, const float* __restrict__ ea,
    const int2* __restrict__ pair, const int* __restrict__ bkbase,
    const float* __restrict__ W1, const float* __restrict__ b1,
    const float* __restrict__ b2,
    const float* __restrict__ W3, const float* __restrict__ b3,
    const float* __restrict__ W4, const float* __restrict__ b4,
    float* __restrict__ base, unsigned* __restrict__ fb)
{
    __shared__ float agg[128][F];    // 5 KB
    __shared__ float w4[ECH*F], w1[NIN*F], w3s[F*F], bb[F], b4s[F];
    int t = threadIdx.x;
    if (t < ECH*F) w4[t] = W4[t];
    if (t < NIN*F) w1[t] = W1[t];
    if (t < F*F)   w3s[t] = W3[t];
    if (t < F) { bb[t] = b1[t] + b2[t] + b3[t]; b4s[t] = b4[t]; }
    for (int i = t; i < 128*F; i += 256) ((float*)agg)[i] = 0.f;
    __syncthreads();

    int b = blockIdx.x;
    int bas = bkbase[b], end = bkbase[b + 1];
    int l = t & 63, wid = t >> 6;
    int g = l >> 2, sub = l & 3, ib = sub * 4;

    for (int p = bas + wid * 16 + g; p < end; p += 64) {
        int2 pr = pair[p];                       // broadcast within 4-lane group
        int eid = pr.y & 0x3FFFFF;
        int dl  = ((unsigned)pr.y) >> 22;
        float4 av = ((const float4*)ea)[(size_t)eid * 4 + sub];
        float ev[F];
#pragma unroll
        for (int j = 0; j < F; ++j) {
            float s0 = av.x * w4[(ib+0)*F + j];
            s0 = fmaf(av.y, w4[(ib+1)*F + j], s0);
            s0 = fmaf(av.z, w4[(ib+2)*F + j], s0);
            s0 = fmaf(av.w, w4[(ib+3)*F + j], s0);
            ev[j] = s0;
        }
#pragma unroll
        for (int j = 0; j < F; ++j) ev[j] += __shfl_xor(ev[j], 1);
#pragma unroll
        for (int j = 0; j < F; ++j) ev[j] += __shfl_xor(ev[j], 2);
        float* row = agg[dl];
#pragma unroll
        for (int k = 0; k < 3; ++k) {            // lane sub handles j = sub, sub+4, sub+8
            int j = sub + 4 * k;
            if (j < F) atomicAdd(row + j, fmaxf(ev[j] + b4s[j], 0.f));
        }
    }
    __syncthreads();

    int n0 = b << BKSH;
    if (t < 128) {
        int n = n0 + t;
        if (n < NN) {
            const float4* px = (const float4*)(x + (size_t)n * NIN);
            float4 x0 = px[0], x1 = px[1], x2 = px[2], x3 = px[3];
            float xv[NIN] = {x0.x,x0.y,x0.z,x0.w, x1.x,x1.y,x1.z,x1.w,
                             x2.x,x2.y,x2.z,x2.w, x3.x,x3.y,x3.z,x3.w};
            float acc[F];
#pragma unroll
            for (int j = 0; j < F; ++j) acc[j] = bb[j];
#pragma unroll
            for (int i = 0; i < NIN; ++i) {
                float xi = xv[i];
#pragma unroll
                for (int j = 0; j < F; ++j) acc[j] = fmaf(xi, w1[i*F + j], acc[j]);
            }
#pragma unroll
            for (int i = 0; i < F; ++i) {
                float ai = agg[t][i];
#pragma unroll
                for (int j = 0; j < F; ++j) acc[j] = fmaf(ai, w3s[i*F + j], acc[j]);
            }
            float4* pb = (float4*)(base + (size_t)n * FP);
            pb[0] = make_float4(acc[0], acc[1], acc[2], acc[3]);
            pb[1] = make_float4(acc[4], acc[5], acc[6], acc[7]);
            pb[2] = make_float4(acc[8], acc[9], 0.f, 0.f);
            pb[3] = make_float4(0.f, 0.f, 0.f, 0.f);
            float fv[F];
#pragma unroll
            for (int j = 0; j < F; ++j) fv[j] = fmaxf(acc[j], 0.f);
            uint4* pf = (uint4*)(fb + (size_t)n * 8);
            pf[0] = make_uint4(pk_bf16(fv[0],fv[1]), pk_bf16(fv[2],fv[3]),
                               pk_bf16(fv[4],fv[5]), pk_bf16(fv[6],fv[7]));
            pf[1] = make_uint4(pk_bf16(fv[8],fv[9]), 0u, 0u, 0u);
        }
    }
}

// ---------- propagation: block per bucket, 3 lanes/edge fb gather (L2), LDS table
__global__ __launch_bounds__(256) void k_iterB(
    const int2* __restrict__ pair, const int* __restrict__ bkbase,
    const unsigned* __restrict__ fbO, const float* __restrict__ base,
    const float* __restrict__ W2,
    unsigned* __restrict__ fbN, float* __restrict__ featN, int last)
{
    __shared__ float agg[128][F];    // 5 KB
    __shared__ float w2[F*F];
    int t = threadIdx.x;
    if (t < F*F) w2[t] = W2[t];
    for (int i = t; i < 128*F; i += 256) ((float*)agg)[i] = 0.f;
    __syncthreads();

    int b = blockIdx.x;
    int bas = bkbase[b], end = bkbase[b + 1];
    int l = t & 63, wid = t >> 6;
    int g = l >> 2, sub = l & 3;

    for (int p = bas + wid * 16 + g; p < end; p += 64) {
        int2 pr = pair[p];                       // broadcast within group
        int s  = pr.x;
        int dl = ((unsigned)pr.y) >> 22;
        float v0 = 0.f, v1 = 0.f, v2 = 0.f, v3 = 0.f;
        if (sub < 3) {
            uint2 q = ((const uint2*)fbO)[(size_t)s * 4 + sub];
            v0 = bf_lo(q.x); v1 = bf_hi(q.x);
            v2 = bf_lo(q.y); v3 = bf_hi(q.y);
        }
        float* row = agg[dl];
        int jb = sub * 4;
        if (jb + 0 < F && sub < 3) atomicAdd(row + jb + 0, v0);
        if (jb + 1 < F && sub < 3) atomicAdd(row + jb + 1, v1);
        if (jb + 2 < F && sub < 3) atomicAdd(row + jb + 2, v2);
        if (jb + 3 < F && sub < 3) atomicAdd(row + jb + 3, v3);
    }
    __syncthreads();

    int n0 = b << BKSH;
    if (t < 128) {
        int n = n0 + t;
        if (n < NN) {
            const unsigned* r = fbO + (size_t)n * 8;     // self row
            uint2 q0 = *(const uint2*)r;
            uint2 q1 = *(const uint2*)(r + 2);
            unsigned q4 = r[4];
            float a[F];
            a[0] = agg[t][0] + bf_lo(q0.x); a[1] = agg[t][1] + bf_hi(q0.x);
            a[2] = agg[t][2] + bf_lo(q0.y); a[3] = agg[t][3] + bf_hi(q0.y);
            a[4] = agg[t][4] + bf_lo(q1.x); a[5] = agg[t][5] + bf_hi(q1.x);
            a[6] = agg[t][6] + bf_lo(q1.y); a[7] = agg[t][7] + bf_hi(q1.y);
            a[8] = agg[t][8] + bf_lo(q4);   a[9] = agg[t][9] + bf_hi(q4);
            const float4* pb = (const float4*)(base + (size_t)n * FP);
            float4 c0 = pb[0], c1 = pb[1], c2 = pb[2];
            float acc[F] = {c0.x,c0.y,c0.z,c0.w, c1.x,c1.y,c1.z,c1.w, c2.x,c2.y};
#pragma unroll
            for (int i = 0; i < F; ++i) {
                float ai = a[i];
#pragma unroll
                for (int j = 0; j < F; ++j) acc[j] = fmaf(ai, w2[i*F + j], acc[j]);
            }
            float fv[F];
#pragma unroll
            for (int j = 0; j < F; ++j) fv[j] = fmaxf(acc[j], 0.f);
            if (!last) {
                uint4* pf = (uint4*)(fbN + (size_t)n * 8);
                pf[0] = make_uint4(pk_bf16(fv[0],fv[1]), pk_bf16(fv[2],fv[3]),
                                   pk_bf16(fv[4],fv[5]), pk_bf16(fv[6],fv[7]));
                pf[1] = make_uint4(pk_bf16(fv[8],fv[9]), 0u, 0u, 0u);
            } else {
                float4* pf = (float4*)(featN + (size_t)n * FP);
                pf[0] = make_float4(fv[0], fv[1], fv[2], fv[3]);
                pf[1] = make_float4(fv[4], fv[5], fv[6], fv[7]);
                pf[2] = make_float4(fv[8], fv[9], 0.f, 0.f);
                pf[3] = make_float4(0.f, 0.f, 0.f, 0.f);
            }
        }
    }
}

// ---------- colsum stage 1
__global__ __launch_bounds__(256) void k_colsum(
    const float* __restrict__ feat, float* __restrict__ cpart)
{
    __shared__ float sm[4][F];
    int t = threadIdx.x;
    float v[F];
#pragma unroll
    for (int j = 0; j < F; ++j) v[j] = 0.f;
    for (int n = blockIdx.x * 256 + t; n < NN; n += CSB * 256) {
        const float4* p = (const float4*)(feat + (size_t)n * FP);
        float4 v0 = p[0], v1 = p[1], v2 = p[2];
        v[0]+=v0.x; v[1]+=v0.y; v[2]+=v0.z; v[3]+=v0.w;
        v[4]+=v1.x; v[5]+=v1.y; v[6]+=v1.z; v[7]+=v1.w;
        v[8]+=v2.x; v[9]+=v2.y;
    }
#pragma unroll
    for (int off = 32; off > 0; off >>= 1) {
#pragma unroll
        for (int j = 0; j < F; ++j) v[j] += __shfl_down(v[j], off);
    }
    int wid = t >> 6;
    if ((t & 63) == 0) {
#pragma unroll
        for (int j = 0; j < F; ++j) sm[wid][j] = v[j];
    }
    __syncthreads();
    if (t < F) {
        float s = sm[0][t] + sm[1][t] + sm[2][t] + sm[3][t];
        cpart[blockIdx.x * F + t] = s;
    }
}

// ---------- tiny global-term finisher
__global__ void k_gsmall(
    const float* __restrict__ cpart, const float* __restrict__ W6,
    const float* __restrict__ b6, const float* __restrict__ W5,
    const float* __restrict__ b5, float* __restrict__ gpart)
{
    __shared__ float gcol[F], r1[F];
    int t = threadIdx.x;
    if (t < F) {
        float s = 0.f;
        for (int b = 0; b < CSB; ++b) s += cpart[b * F + t];
        gcol[t] = s;
    }
    __syncthreads();
    if (t < F) {
        float acc = b6[t];
        for (int i = 0; i < F; ++i) acc = fmaf(gcol[i], W6[i*F + t], acc);
        r1[t] = acc > 0.f ? acc : 0.f;
    }
    __syncthreads();
    if (t < OC) {
        float acc = b5[t];
        for (int i = 0; i < F; ++i) acc = fmaf(r1[i], W5[i*OC + t], acc);
        gpart[t] = acc;
    }
}

// ---------- output
__global__ __launch_bounds__(256) void k_out(
    const float* __restrict__ feat, const float* __restrict__ W7,
    const float* __restrict__ b7, const float* __restrict__ W5,
    const float* __restrict__ gpart, float* __restrict__ out)
{
    __shared__ float w7[F*F], bb7[F], w5[F*OC], gp[OC];
    int t = threadIdx.x;
    if (t < F*F) w7[t] = W7[t];
    if (t < F) bb7[t] = b7[t];
    for (int i = t; i < F*OC; i += 256) w5[i] = W5[F*OC + i];
    if (t < OC) gp[t] = gpart[t];
    __syncthreads();
    int n = blockIdx.x * 256 + t;
    if (n >= NN) return;
    const float4* p = (const float4*)(feat + (size_t)n * FP);
    float4 v0 = p[0], v1 = p[1], v2 = p[2];
    float f[F] = {v0.x,v0.y,v0.z,v0.w, v1.x,v1.y,v1.z,v1.w, v2.x,v2.y};
    float h[F];
#pragma unroll
    for (int j = 0; j < F; ++j) h[j] = bb7[j];
#pragma unroll
    for (int i = 0; i < F; ++i) {
        float fi = f[i];
#pragma unroll
        for (int j = 0; j < F; ++j) h[j] = fmaf(fi, w7[i*F + j], h[j]);
    }
#pragma unroll
    for (int j = 0; j < F; ++j) h[j] = h[j] > 0.f ? h[j] : 0.f;
    float o[OC];
#pragma unroll
    for (int k = 0; k < OC; ++k) o[k] = gp[k];
#pragma unroll
    for (int j = 0; j < F; ++j) {
        float hj = h[j];
#pragma unroll
        for (int k = 0; k < OC; ++k) o[k] = fmaf(hj, w5[j*OC + k], o[k]);
    }
    float4* po = (float4*)(out + (size_t)n * OC);
#pragma unroll
    for (int k = 0; k < 8; ++k)
        po[k] = make_float4(o[4*k], o[4*k+1], o[4*k+2], o[4*k+3]);
}

extern "C" void kernel_launch(void* const* d_in, const int* in_sizes, int n_in,
                              void* d_out, int out_size, void* d_ws, size_t ws_size,
                              hipStream_t stream)
{
    const float* x   = (const float*)d_in[0];
    const int*   ei  = (const int*)d_in[1];
    const float* ea  = (const float*)d_in[2];
    const float* W1  = (const float*)d_in[3];
    const float* b1  = (const float*)d_in[4];
    const float* W2  = (const float*)d_in[5];
    const float* b2  = (const float*)d_in[6];
    const float* W3  = (const float*)d_in[7];
    const float* b3  = (const float*)d_in[8];
    const float* W4  = (const float*)d_in[9];
    const float* b4  = (const float*)d_in[10];
    const float* W5  = (const float*)d_in[11];
    const float* b5  = (const float*)d_in[12];
    const float* W6  = (const float*)d_in[13];
    const float* b6  = (const float*)d_in[14];
    const float* W7  = (const float*)d_in[15];
    const float* b7  = (const float*)d_in[16];

    const int* src = ei;            // edge_index[0]
    const int* dst = ei + NE;       // edge_index[1]

    // workspace layout (16B-aligned chunks)
    char* w = (char*)d_ws;
    int2* pair    = (int2*)w;                  w += (size_t)NE * 8;        // 25.6 MB
    float* base   = (float*)w;                 w += (size_t)NN * FP * 4;   // 6.4 MB
    float* featA  = (float*)w;                 w += (size_t)NN * FP * 4;
    unsigned* fbA = (unsigned*)w;              w += (size_t)NN * 32;       // 3.2 MB
    unsigned* fbB = (unsigned*)w;              w += (size_t)NN * 32;
    int* bkcnt    = (int*)w;                   w += (size_t)NBK * 4;       // zeroed
    int* cur      = (int*)w;                   w += (size_t)NBK * 4;       // zeroed (contiguous)
    int* bkbase   = (int*)w;                   w += (size_t)(NBK + 16) * 4;
    float* cpart  = (float*)w;                 w += (size_t)CSB * F * 4;
    float* gpart  = (float*)w;                 w += 32 * 4;

    const int NB = (NN + 255) / 256;           // 391
    const int SB = (NE + CH - 1) / CH;         // 391

    hipMemsetAsync(bkcnt, 0, (size_t)2 * NBK * 4, stream);   // bkcnt + cur

    k_binhist<<<512, 256, 0, stream>>>(dst, bkcnt);
    k_bkscan <<<1, 1024, 0, stream>>>(bkcnt, bkbase);
    k_binscat<<<SB, 256, 0, stream>>>(src, dst, bkbase, cur, pair);

    k_initB  <<<NBK, 256, 0, stream>>>(x, ea, pair, bkbase,
                                       W1, b1, b2, W3, b3, W4, b4, base, fbA);

    k_iterB  <<<NBK, 256, 0, stream>>>(pair, bkbase, fbA, base, W2,
                                       fbB, (float*)nullptr, 0);
    k_iterB  <<<NBK, 256, 0, stream>>>(pair, bkbase, fbB, base, W2,
                                       (unsigned*)nullptr, featA, 1);

    k_colsum <<<CSB, 256, 0, stream>>>(featA, cpart);
    k_gsmall <<<1, 64, 0, stream>>>(cpart, W6, b6, W5, b5, gpart);
    k_out    <<<NB, 256, 0, stream>>>(featA, W7, b7, W5, gpart, (float*)d_out);
}

// Round 12
// 473.892 us; speedup vs baseline: 1.7975x; 1.7635x over previous
//
#include <hip/hip_runtime.h>

#define NN 100000
#define NE 3200000
#define NIN 16
#define ECH 16
#define F 10
#define FP 16          // padded node row stride = 64 B
#define OC 32
#define CSB 104        // colsum stage-1 blocks
#define BKSH 7         // 128 nodes per bucket
#define NBK 782        // ceil(NN / 128)
#define CH 8192        // edges per binscat block

__device__ __forceinline__ unsigned pk_bf16(float a, float b) {
    unsigned ua = __float_as_uint(a); ua = (ua + 0x7FFFu + ((ua >> 16) & 1u)) >> 16;
    unsigned ub = __float_as_uint(b); ub = (ub + 0x7FFFu + ((ub >> 16) & 1u)) >> 16;
    return ua | (ub << 16);
}
__device__ __forceinline__ float bf_lo(unsigned u) { return __uint_as_float(u << 16); }
__device__ __forceinline__ float bf_hi(unsigned u) { return __uint_as_float(u & 0xFFFF0000u); }

// ---------- bucket histogram
__global__ __launch_bounds__(256) void k_binhist(const int* __restrict__ dst,
                                                 int* __restrict__ bkcnt)
{
    __shared__ int lcnt[NBK];
    int t = threadIdx.x;
    for (int k = t; k < NBK; k += 256) lcnt[k] = 0;
    __syncthreads();
    for (int e = blockIdx.x * 256 + t; e < NE; e += gridDim.x * 256)
        atomicAdd(&lcnt[dst[e] >> BKSH], 1);
    __syncthreads();
    for (int k = t; k < NBK; k += 256) {
        int v = lcnt[k];
        if (v) atomicAdd(&bkcnt[k], v);
    }
}

// ---------- scan of bucket counts
__global__ __launch_bounds__(1024) void k_bkscan(const int* __restrict__ bkcnt,
                                                 int* __restrict__ bkbase,
                                                 int* __restrict__ offs)
{
    __shared__ int wsum[16], wscan[16];
    int t = threadIdx.x;
    int v = (t < NBK) ? bkcnt[t] : 0;
    int lane = t & 63, w = t >> 6;
    int inc = v;
    for (int d = 1; d < 64; d <<= 1) { int u = __shfl_up(inc, d); if (lane >= d) inc += u; }
    if (lane == 63) wsum[w] = inc;
    __syncthreads();
    if (t < 16) {
        int u = wsum[t];
        for (int d = 1; d < 16; d <<= 1) { int x2 = __shfl_up(u, d); if (t >= d) u += x2; }
        wscan[t] = u;
    }
    __syncthreads();
    int excl = inc - v + (w > 0 ? wscan[w - 1] : 0);
    if (t < NBK) bkbase[t] = excl;
    if (t == 0) { bkbase[NBK] = NE; offs[NN] = NE; }
}

// ---------- bin scatter: one 8B int2 {src, dlocal<<22|eid} per edge into bucket runs
__global__ __launch_bounds__(256) void k_binscat(
    const int* __restrict__ src, const int* __restrict__ dst,
    const int* __restrict__ bkbase, int* __restrict__ cur,
    int2* __restrict__ pair)
{
    __shared__ int lcnt[NBK];
    __shared__ int lbb[NBK];
    int t = threadIdx.x;
    int e0 = blockIdx.x * CH;
    int e1 = e0 + CH; if (e1 > NE) e1 = NE;
    for (int k = t; k < NBK; k += 256) lcnt[k] = 0;
    __syncthreads();
    for (int e = e0 + t; e < e1; e += 256)
        atomicAdd(&lcnt[dst[e] >> BKSH], 1);
    __syncthreads();
    for (int k = t; k < NBK; k += 256) {
        int c = lcnt[k];
        lbb[k] = c ? (bkbase[k] + atomicAdd(&cur[k], c)) : 0;
        lcnt[k] = 0;
    }
    __syncthreads();
    for (int e = e0 + t; e < e1; e += 256) {
        int d = dst[e];
        int bk = d >> BKSH;
        int idx = atomicAdd(&lcnt[bk], 1);
        pair[lbb[bk] + idx] = make_int2(src[e], ((d & 127) << 22) | e);
    }
}

// ---------- per-bucket counting sort into final CSR (scatter stays in L2)
__global__ __launch_bounds__(256) void k_lsort(
    const int* __restrict__ bkbase, const int2* __restrict__ pair,
    int* __restrict__ offs, int* __restrict__ srcs, int* __restrict__ eids)
{
    __shared__ int lcnt[128];
    __shared__ int lcur[128];
    __shared__ int s0tot;
    int t = threadIdx.x;
    int b = blockIdx.x;
    int base = bkbase[b];
    int cnt = bkbase[b + 1] - base;
    int n0 = b << BKSH;
    int nodes = NN - n0; if (nodes > 128) nodes = 128;

    if (t < 128) lcnt[t] = 0;
    __syncthreads();
    for (int i = t; i < cnt; i += 256)
        atomicAdd(&lcnt[((unsigned)pair[base + i].y) >> 22], 1);
    __syncthreads();
    if (t < 128) {
        int v = lcnt[t];
        int lane = t & 63, w = t >> 6;
        int inc = v;
        for (int d = 1; d < 64; d <<= 1) { int u = __shfl_up(inc, d); if (lane >= d) inc += u; }
        if (w == 0 && lane == 63) s0tot = inc;
        __syncthreads();
        int excl = inc - v + (w == 1 ? s0tot : 0);
        lcur[t] = base + excl;
        if (t < nodes) offs[n0 + t] = base + excl;
    } else {
        __syncthreads();
    }
    __syncthreads();
    for (int i = t; i < cnt; i += 256) {
        int2 pr = pair[base + i];
        int pe = pr.y;
        int pos = atomicAdd(&lcur[((unsigned)pe) >> 22], 1);
        srcs[pos] = pr.x;
        eids[pos] = pe & 0x3FFFFF;
    }
}

// ---------- L3 prewarm: stream-read ea sequentially so random gathers hit L3
__global__ __launch_bounds__(256) void k_warm(const float4* __restrict__ ea4,
                                              float* __restrict__ sink)
{
    const int TOT = NE * ECH / 4;         // 12.8M float4
    float s = 0.f;
    for (int i = blockIdx.x * 256 + threadIdx.x; i < TOT; i += gridDim.x * 256) {
        float4 v = ea4[i];
        s = fmaf(v.x, 1.0f, s); s = fmaf(v.y, 1.0f, s);
        s = fmaf(v.z, 1.0f, s); s = fmaf(v.w, 1.0f, s);
    }
    if (s == -1.2345678e30f) sink[0] = s;   // never taken; keeps loads alive
}

// ---------- fused init: wave/node, 4 lanes/edge, 2-way unrolled ea gather
// writes base (f32) and fb (bf16 packed, 32B/node)
__global__ __launch_bounds__(256) void k_init(
    const float* __restrict__ x, const float* __restrict__ ea,
    const int* __restrict__ eids, const int* __restrict__ offs,
    const float* __restrict__ W1, const float* __restrict__ b1,
    const float* __restrict__ b2,
    const float* __restrict__ W3, const float* __restrict__ b3,
    const float* __restrict__ W4, const float* __restrict__ b4,
    float* __restrict__ base, unsigned* __restrict__ fb)
{
    __shared__ float w1[NIN*F], w3[F*F], w4[ECH*F], bb[F], b4s[F];
    int t = threadIdx.x;
    if (t < NIN*F) w1[t] = W1[t];
    if (t < F*F)   w3[t] = W3[t];
    if (t < ECH*F) w4[t] = W4[t];
    if (t < F) { bb[t] = b1[t] + b2[t] + b3[t]; b4s[t] = b4[t]; }
    __syncthreads();

    int wid = t >> 6, l = t & 63;
    int n = blockIdx.x * 4 + wid;
    bool valid = n < NN;
    int p0 = 0, p1 = 0;
    if (valid) { p0 = offs[n]; p1 = offs[n + 1]; }
    int g = l >> 2, sub = l & 3;
    int ib = sub * 4;

    float acc[F];
#pragma unroll
    for (int j = 0; j < F; ++j) acc[j] = 0.f;

    int p = p0 + g;
    for (; p + 16 < p1; p += 32) {
        int e0 = eids[p], e1 = eids[p + 16];
        float4 av0 = ((const float4*)(ea + (size_t)e0 * ECH))[sub];
        float4 av1 = ((const float4*)(ea + (size_t)e1 * ECH))[sub];
        float ev0[F], ev1[F];
#pragma unroll
        for (int j = 0; j < F; ++j) {
            float s0 = fmaf(av0.x, w4[(ib+0)*F + j], 0.f);
            s0 = fmaf(av0.y, w4[(ib+1)*F + j], s0);
            s0 = fmaf(av0.z, w4[(ib+2)*F + j], s0);
            s0 = fmaf(av0.w, w4[(ib+3)*F + j], s0);
            ev0[j] = s0;
            float s1 = fmaf(av1.x, w4[(ib+0)*F + j], 0.f);
            s1 = fmaf(av1.y, w4[(ib+1)*F + j], s1);
            s1 = fmaf(av1.z, w4[(ib+2)*F + j], s1);
            s1 = fmaf(av1.w, w4[(ib+3)*F + j], s1);
            ev1[j] = s1;
        }
#pragma unroll
        for (int j = 0; j < F; ++j) { ev0[j] += __shfl_xor(ev0[j], 1); ev1[j] += __shfl_xor(ev1[j], 1); }
#pragma unroll
        for (int j = 0; j < F; ++j) { ev0[j] += __shfl_xor(ev0[j], 2); ev1[j] += __shfl_xor(ev1[j], 2); }
#pragma unroll
        for (int j = 0; j < F; ++j)
            acc[j] += fmaxf(ev0[j] + b4s[j], 0.f) + fmaxf(ev1[j] + b4s[j], 0.f);
    }
    if (p < p1) {
        int e0 = eids[p];
        float4 av = ((const float4*)(ea + (size_t)e0 * ECH))[sub];
        float ev[F];
#pragma unroll
        for (int j = 0; j < F; ++j) {
            float s0 = fmaf(av.x, w4[(ib+0)*F + j], 0.f);
            s0 = fmaf(av.y, w4[(ib+1)*F + j], s0);
            s0 = fmaf(av.z, w4[(ib+2)*F + j], s0);
            s0 = fmaf(av.w, w4[(ib+3)*F + j], s0);
            ev[j] = s0;
        }
#pragma unroll
        for (int j = 0; j < F; ++j) ev[j] += __shfl_xor(ev[j], 1);
#pragma unroll
        for (int j = 0; j < F; ++j) ev[j] += __shfl_xor(ev[j], 2);
#pragma unroll
        for (int j = 0; j < F; ++j) acc[j] += fmaxf(ev[j] + b4s[j], 0.f);
    }
#pragma unroll
    for (int m = 4; m < 64; m <<= 1) {
#pragma unroll
        for (int j = 0; j < F; ++j) acc[j] += __shfl_xor(acc[j], m);
    }

    float fv = 0.f;
    if (valid) {
        int j = l;
        if (j < F) {
            float a = bb[j];
#pragma unroll
            for (int i = 0; i < NIN; ++i)
                a = fmaf(x[(size_t)n * NIN + i], w1[i*F + j], a);
#pragma unroll
            for (int i = 0; i < F; ++i)
                a = fmaf(acc[i], w3[i*F + j], a);
            base[(size_t)n * FP + j] = a;
            fv = fmaxf(a, 0.f);
        } else if (j < FP) {
            base[(size_t)n * FP + j] = 0.f;
        }
    }
    float partner = __shfl_xor(fv, 1);
    if (valid && l < 16 && (l & 1) == 0)
        fb[(size_t)n * 8 + (l >> 1)] = pk_bf16(fv, partner);
}

// ---------- propagation: wave/node, 4 lanes/edge, bf16 L2-resident gather, 2-way unroll
__global__ __launch_bounds__(256) void k_iter(
    const int* __restrict__ srcs, const int* __restrict__ offs,
    const uint2* __restrict__ fbO, const float* __restrict__ base,
    const float* __restrict__ W2,
    unsigned* __restrict__ fbN, float* __restrict__ featN,
    int wfb, int wf32)
{
    __shared__ float w2[F*F];
    __shared__ float sm[4][16];
    int t = threadIdx.x;
    if (t < F*F) w2[t] = W2[t];
    __syncthreads();

    int wid = t >> 6, l = t & 63;
    int n = blockIdx.x * 4 + wid;
    bool valid = n < NN;
    int p0 = 0, p1 = 0;
    if (valid) { p0 = offs[n]; p1 = offs[n + 1]; }
    int g = l >> 2, sub = l & 3;

    float4 a4 = make_float4(0.f, 0.f, 0.f, 0.f);
    int p = p0 + g;
    for (; p + 16 < p1; p += 32) {
        int s0 = srcs[p], s1 = srcs[p + 16];
        uint2 v0 = fbO[(size_t)s0 * 4 + sub];
        uint2 v1 = fbO[(size_t)s1 * 4 + sub];
        a4.x += bf_lo(v0.x) + bf_lo(v1.x);
        a4.y += bf_hi(v0.x) + bf_hi(v1.x);
        a4.z += bf_lo(v0.y) + bf_lo(v1.y);
        a4.w += bf_hi(v0.y) + bf_hi(v1.y);
    }
    if (p < p1) {
        int s0 = srcs[p];
        uint2 v0 = fbO[(size_t)s0 * 4 + sub];
        a4.x += bf_lo(v0.x); a4.y += bf_hi(v0.x);
        a4.z += bf_lo(v0.y); a4.w += bf_hi(v0.y);
    }
#pragma unroll
    for (int m = 4; m < 64; m <<= 1) {
        a4.x += __shfl_xor(a4.x, m); a4.y += __shfl_xor(a4.y, m);
        a4.z += __shfl_xor(a4.z, m); a4.w += __shfl_xor(a4.w, m);
    }
    if (valid && l < 4) {
        uint2 sv = fbO[(size_t)n * 4 + l];
        sm[wid][l*4+0] = a4.x + bf_lo(sv.x); sm[wid][l*4+1] = a4.y + bf_hi(sv.x);
        sm[wid][l*4+2] = a4.z + bf_lo(sv.y); sm[wid][l*4+3] = a4.w + bf_hi(sv.y);
    }
    __syncthreads();
    float fv = 0.f;
    if (valid && l < F) {
        float a = base[(size_t)n * FP + l];
#pragma unroll
        for (int i = 0; i < F; ++i)
            a = fmaf(sm[wid][i], w2[i*F + l], a);
        fv = fmaxf(a, 0.f);
    }
    float partner = __shfl_xor(fv, 1);
    if (valid) {
        if (wfb && l < 16 && (l & 1) == 0)
            fbN[(size_t)n * 8 + (l >> 1)] = pk_bf16(fv, partner);
        if (wf32) {
            if (l < F) featN[(size_t)n * FP + l] = fv;
            else if (l < FP) featN[(size_t)n * FP + l] = 0.f;
        }
    }
}

// ---------- colsum stage 1
__global__ __launch_bounds__(256) void k_colsum(
    const float* __restrict__ feat, float* __restrict__ cpart)
{
    __shared__ float sm[4][F];
    int t = threadIdx.x;
    float v[F];
#pragma unroll
    for (int j = 0; j < F; ++j) v[j] = 0.f;
    for (int n = blockIdx.x * 256 + t; n < NN; n += CSB * 256) {
        const float4* p = (const float4*)(feat + (size_t)n * FP);
        float4 v0 = p[0], v1 = p[1], v2 = p[2];
        v[0]+=v0.x; v[1]+=v0.y; v[2]+=v0.z; v[3]+=v0.w;
        v[4]+=v1.x; v[5]+=v1.y; v[6]+=v1.z; v[7]+=v1.w;
        v[8]+=v2.x; v[9]+=v2.y;
    }
#pragma unroll
    for (int off = 32; off > 0; off >>= 1) {
#pragma unroll
        for (int j = 0; j < F; ++j) v[j] += __shfl_down(v[j], off);
    }
    int wid = t >> 6;
    if ((t & 63) == 0) {
#pragma unroll
        for (int j = 0; j < F; ++j) sm[wid][j] = v[j];
    }
    __syncthreads();
    if (t < F) {
        float s = sm[0][t] + sm[1][t] + sm[2][t] + sm[3][t];
        cpart[blockIdx.x * F + t] = s;
    }
}

// ---------- tiny global-term finisher
__global__ void k_gsmall(
    const float* __restrict__ cpart, const float* __restrict__ W6,
    const float* __restrict__ b6, const float* __restrict__ W5,
    const float* __restrict__ b5, float* __restrict__ gpart)
{
    __shared__ float gcol[F], r1[F];
    int t = threadIdx.x;
    if (t < F) {
        float s = 0.f;
        for (int b = 0; b < CSB; ++b) s += cpart[b * F + t];
        gcol[t] = s;
    }
    __syncthreads();
    if (t < F) {
        float acc = b6[t];
        for (int i = 0; i < F; ++i) acc = fmaf(gcol[i], W6[i*F + t], acc);
        r1[t] = acc > 0.f ? acc : 0.f;
    }
    __syncthreads();
    if (t < OC) {
        float acc = b5[t];
        for (int i = 0; i < F; ++i) acc = fmaf(r1[i], W5[i*OC + t], acc);
        gpart[t] = acc;
    }
}

// ---------- output
__global__ __launch_bounds__(256) void k_out(
    const float* __restrict__ feat, const float* __restrict__ W7,
    const float* __restrict__ b7, const float* __restrict__ W5,
    const float* __restrict__ gpart, float* __restrict__ out)
{
    __shared__ float w7[F*F], bb7[F], w5[F*OC], gp[OC];
    int t = threadIdx.x;
    if (t < F*F) w7[t] = W7[t];
    if (t < F) bb7[t] = b7[t];
    for (int i = t; i < F*OC; i += 256) w5[i] = W5[F*OC + i];
    if (t < OC) gp[t] = gpart[t];
    __syncthreads();
    int n = blockIdx.x * 256 + t;
    if (n >= NN) return;
    const float4* p = (const float4*)(feat + (size_t)n * FP);
    float4 v0 = p[0], v1 = p[1], v2 = p[2];
    float f[F] = {v0.x,v0.y,v0.z,v0.w, v1.x,v1.y,v1.z,v1.w, v2.x,v2.y};
    float h[F];
#pragma unroll
    for (int j = 0; j < F; ++j) h[j] = bb7[j];
#pragma unroll
    for (int i = 0; i < F; ++i) {
        float fi = f[i];
#pragma unroll
        for (int j = 0; j < F; ++j) h[j] = fmaf(fi, w7[i*F + j], h[j]);
    }
#pragma unroll
    for (int j = 0; j < F; ++j) h[j] = h[j] > 0.f ? h[j] : 0.f;
    float o[OC];
#pragma unroll
    for (int k = 0; k < OC; ++k) o[k] = gp[k];
#pragma unroll
    for (int j = 0; j < F; ++j) {
        float hj = h[j];
#pragma unroll
        for (int k = 0; k < OC; ++k) o[k] = fmaf(hj, w5[j*OC + k], o[k]);
    }
    float4* po = (float4*)(out + (size_t)n * OC);
#pragma unroll
    for (int k = 0; k < 8; ++k)
        po[k] = make_float4(o[4*k], o[4*k+1], o[4*k+2], o[4*k+3]);
}

extern "C" void kernel_launch(void* const* d_in, const int* in_sizes, int n_in,
                              void* d_out, int out_size, void* d_ws, size_t ws_size,
                              hipStream_t stream)
{
    const float* x   = (const float*)d_in[0];
    const int*   ei  = (const int*)d_in[1];
    const float* ea  = (const float*)d_in[2];
    const float* W1  = (const float*)d_in[3];
    const float* b1  = (const float*)d_in[4];
    const float* W2  = (const float*)d_in[5];
    const float* b2  = (const float*)d_in[6];
    const float* W3  = (const float*)d_in[7];
    const float* b3  = (const float*)d_in[8];
    const float* W4  = (const float*)d_in[9];
    const float* b4  = (const float*)d_in[10];
    const float* W5  = (const float*)d_in[11];
    const float* b5  = (const float*)d_in[12];
    const float* W6  = (const float*)d_in[13];
    const float* b6  = (const float*)d_in[14];
    const float* W7  = (const float*)d_in[15];
    const float* b7  = (const float*)d_in[16];

    const int* src = ei;            // edge_index[0]
    const int* dst = ei + NE;       // edge_index[1]

    // workspace layout (16B-aligned chunks)
    char* w = (char*)d_ws;
    int2* pair   = (int2*)w;                   w += (size_t)NE * 8;        // 25.6 MB
    int* srcs    = (int*)w;                    w += (size_t)NE * 4;        // 12.8 MB
    int* eids    = (int*)w;                    w += (size_t)NE * 4;
    float* base  = (float*)w;                  w += (size_t)NN * FP * 4;   // 6.4 MB
    float* featA = (float*)w;                  w += (size_t)NN * FP * 4;
    unsigned* fbA = (unsigned*)w;              w += (size_t)NN * 32;       // 3.2 MB
    unsigned* fbB = (unsigned*)w;              w += (size_t)NN * 32;
    int* offs    = (int*)w;                    w += (size_t)(NN + 16) * 4;
    int* bkcnt   = (int*)w;                    w += (size_t)NBK * 4;       // zeroed
    int* cur     = (int*)w;                    w += (size_t)NBK * 4;       // zeroed (contiguous)
    int* bkbase  = (int*)w;                    w += (size_t)(NBK + 16) * 4;
    float* cpart = (float*)w;                  w += (size_t)CSB * F * 4;
    float* gpart = (float*)w;                  w += 32 * 4;
    float* sink  = (float*)w;                  w += 16 * 4;

    const int NB = (NN + 255) / 256;           // 391
    const int WB = (NN + 3) / 4;               // 25000
    const int SB = (NE + CH - 1) / CH;         // 391

    hipMemsetAsync(bkcnt, 0, (size_t)2 * NBK * 4, stream);   // bkcnt + cur

    k_binhist<<<512, 256, 0, stream>>>(dst, bkcnt);
    k_bkscan <<<1, 1024, 0, stream>>>(bkcnt, bkbase, offs);
    k_binscat<<<SB, 256, 0, stream>>>(src, dst, bkbase, cur, pair);
    k_lsort  <<<NBK, 256, 0, stream>>>(bkbase, pair, offs, srcs, eids);

    // L3 prewarm of ea right before the random gather
    k_warm   <<<2048, 256, 0, stream>>>((const float4*)ea, sink);

    k_init   <<<WB, 256, 0, stream>>>(x, ea, eids, offs, W1, b1, b2, W3, b3,
                                      W4, b4, base, fbA);

    k_iter   <<<WB, 256, 0, stream>>>(srcs, offs, (const uint2*)fbA, base, W2,
                                      fbB, (float*)nullptr, 1, 0);
    k_iter   <<<WB, 256, 0, stream>>>(srcs, offs, (const uint2*)fbB, base, W2,
                                      (unsigned*)nullptr, featA, 0, 1);

    k_colsum <<<CSB, 256, 0, stream>>>(featA, cpart);
    k_gsmall <<<1, 64, 0, stream>>>(cpart, W6, b6, W5, b5, gpart);
    k_out    <<<NB, 256, 0, stream>>>(featA, W7, b7, W5, gpart, (float*)d_out);
}

// Round 13
// 434.889 us; speedup vs baseline: 1.9587x; 1.0897x over previous
//
#include <hip/hip_runtime.h>

#define NN 100000
#define NE 3200000
#define NIN 16
#define ECH 16
#define F 10
#define FP 16          // padded node row stride = 64 B
#define OC 32
#define CSB 104        // colsum stage-1 blocks
#define BKSH 7         // 128 nodes per bucket
#define NBK 782        // ceil(NN / 128)
#define CH 8192        // edges per binscat block
#define CAP 5120       // fixed tmp capacity per bucket (mean 4096, +16 sigma)

__device__ __forceinline__ unsigned pk_bf16(float a, float b) {
    unsigned ua = __float_as_uint(a); ua = (ua + 0x7FFFu + ((ua >> 16) & 1u)) >> 16;
    unsigned ub = __float_as_uint(b); ub = (ub + 0x7FFFu + ((ub >> 16) & 1u)) >> 16;
    return ua | (ub << 16);
}
__device__ __forceinline__ float bf_lo(unsigned u) { return __uint_as_float(u << 16); }
__device__ __forceinline__ float bf_hi(unsigned u) { return __uint_as_float(u & 0xFFFF0000u); }

// ---------- bin scatter into fixed-capacity strided tmp (no prior histogram)
__global__ __launch_bounds__(256) void k_binscat(
    const int* __restrict__ src, const int* __restrict__ dst,
    int* __restrict__ cur, int2* __restrict__ pair)
{
    __shared__ int lcnt[NBK];
    __shared__ int lbb[NBK];
    int t = threadIdx.x;
    int e0 = blockIdx.x * CH;
    int e1 = e0 + CH; if (e1 > NE) e1 = NE;
    for (int k = t; k < NBK; k += 256) lcnt[k] = 0;
    __syncthreads();
    for (int e = e0 + t; e < e1; e += 256)
        atomicAdd(&lcnt[dst[e] >> BKSH], 1);
    __syncthreads();
    for (int k = t; k < NBK; k += 256) {
        int c = lcnt[k];
        lbb[k] = c ? (k * CAP + atomicAdd(&cur[k], c)) : 0;
        lcnt[k] = 0;
    }
    __syncthreads();
    for (int e = e0 + t; e < e1; e += 256) {
        int d = dst[e];
        int bk = d >> BKSH;
        int idx = atomicAdd(&lcnt[bk], 1);
        pair[lbb[bk] + idx] = make_int2(src[e], ((d & 127) << 22) | e);
    }
}

// ---------- scan of bucket counts (cur) -> compact bkbase
__global__ __launch_bounds__(1024) void k_bkscan(const int* __restrict__ cnt,
                                                 int* __restrict__ bkbase,
                                                 int* __restrict__ offs)
{
    __shared__ int wsum[16], wscan[16];
    int t = threadIdx.x;
    int v = (t < NBK) ? cnt[t] : 0;
    int lane = t & 63, w = t >> 6;
    int inc = v;
    for (int d = 1; d < 64; d <<= 1) { int u = __shfl_up(inc, d); if (lane >= d) inc += u; }
    if (lane == 63) wsum[w] = inc;
    __syncthreads();
    if (t < 16) {
        int u = wsum[t];
        for (int d = 1; d < 16; d <<= 1) { int x2 = __shfl_up(u, d); if (t >= d) u += x2; }
        wscan[t] = u;
    }
    __syncthreads();
    int excl = inc - v + (w > 0 ? wscan[w - 1] : 0);
    if (t < NBK) bkbase[t] = excl;
    if (t == 0) { bkbase[NBK] = NE; offs[NN] = NE; }
}

// ---------- per-bucket counting sort: strided tmp -> compact node-sorted CSR
__global__ __launch_bounds__(256) void k_lsort(
    const int* __restrict__ bkbase, const int2* __restrict__ pair,
    int* __restrict__ offs, int* __restrict__ srcs, int* __restrict__ eids)
{
    __shared__ int lcnt[128];
    __shared__ int lcur[128];
    __shared__ int s0tot;
    int t = threadIdx.x;
    int b = blockIdx.x;
    int base = bkbase[b];
    int cnt = bkbase[b + 1] - base;
    const int2* tp = pair + (size_t)b * CAP;
    int n0 = b << BKSH;
    int nodes = NN - n0; if (nodes > 128) nodes = 128;

    if (t < 128) lcnt[t] = 0;
    __syncthreads();
    for (int i = t; i < cnt; i += 256)
        atomicAdd(&lcnt[((unsigned)tp[i].y) >> 22], 1);
    __syncthreads();
    if (t < 128) {
        int v = lcnt[t];
        int lane = t & 63, w = t >> 6;
        int inc = v;
        for (int d = 1; d < 64; d <<= 1) { int u = __shfl_up(inc, d); if (lane >= d) inc += u; }
        if (w == 0 && lane == 63) s0tot = inc;
        __syncthreads();
        int excl = inc - v + (w == 1 ? s0tot : 0);
        lcur[t] = base + excl;
        if (t < nodes) offs[n0 + t] = base + excl;
    } else {
        __syncthreads();
    }
    __syncthreads();
    for (int i = t; i < cnt; i += 256) {
        int2 pr = tp[i];
        int pe = pr.y;
        int pos = atomicAdd(&lcur[((unsigned)pe) >> 22], 1);
        srcs[pos] = pr.x;
        eids[pos] = pe & 0x3FFFFF;
    }
}

// ---------- fused init: wave/node, 4 lanes/edge, 2-way unrolled ea gather
// writes base (f32) and fb (bf16 packed, 32B/node)
__global__ __launch_bounds__(256) void k_init(
    const float* __restrict__ x, const float* __restrict__ ea,
    const int* __restrict__ eids, const int* __restrict__ offs,
    const float* __restrict__ W1, const float* __restrict__ b1,
    const float* __restrict__ b2,
    const float* __restrict__ W3, const float* __restrict__ b3,
    const float* __restrict__ W4, const float* __restrict__ b4,
    float* __restrict__ base, unsigned* __restrict__ fb)
{
    __shared__ float w1[NIN*F], w3[F*F], w4[ECH*F], bb[F], b4s[F];
    int t = threadIdx.x;
    if (t < NIN*F) w1[t] = W1[t];
    if (t < F*F)   w3[t] = W3[t];
    if (t < ECH*F) w4[t] = W4[t];
    if (t < F) { bb[t] = b1[t] + b2[t] + b3[t]; b4s[t] = b4[t]; }
    __syncthreads();

    int wid = t >> 6, l = t & 63;
    int n = blockIdx.x * 4 + wid;
    bool valid = n < NN;
    int p0 = 0, p1 = 0;
    if (valid) { p0 = offs[n]; p1 = offs[n + 1]; }
    int g = l >> 2, sub = l & 3;
    int ib = sub * 4;

    float acc[F];
#pragma unroll
    for (int j = 0; j < F; ++j) acc[j] = 0.f;

    int p = p0 + g;
    for (; p + 16 < p1; p += 32) {
        int e0 = eids[p], e1 = eids[p + 16];
        float4 av0 = ((const float4*)(ea + (size_t)e0 * ECH))[sub];
        float4 av1 = ((const float4*)(ea + (size_t)e1 * ECH))[sub];
        float ev0[F], ev1[F];
#pragma unroll
        for (int j = 0; j < F; ++j) {
            float s0 = fmaf(av0.x, w4[(ib+0)*F + j], 0.f);
            s0 = fmaf(av0.y, w4[(ib+1)*F + j], s0);
            s0 = fmaf(av0.z, w4[(ib+2)*F + j], s0);
            s0 = fmaf(av0.w, w4[(ib+3)*F + j], s0);
            ev0[j] = s0;
            float s1 = fmaf(av1.x, w4[(ib+0)*F + j], 0.f);
            s1 = fmaf(av1.y, w4[(ib+1)*F + j], s1);
            s1 = fmaf(av1.z, w4[(ib+2)*F + j], s1);
            s1 = fmaf(av1.w, w4[(ib+3)*F + j], s1);
            ev1[j] = s1;
        }
#pragma unroll
        for (int j = 0; j < F; ++j) { ev0[j] += __shfl_xor(ev0[j], 1); ev1[j] += __shfl_xor(ev1[j], 1); }
#pragma unroll
        for (int j = 0; j < F; ++j) { ev0[j] += __shfl_xor(ev0[j], 2); ev1[j] += __shfl_xor(ev1[j], 2); }
#pragma unroll
        for (int j = 0; j < F; ++j)
            acc[j] += fmaxf(ev0[j] + b4s[j], 0.f) + fmaxf(ev1[j] + b4s[j], 0.f);
    }
    if (p < p1) {
        int e0 = eids[p];
        float4 av = ((const float4*)(ea + (size_t)e0 * ECH))[sub];
        float ev[F];
#pragma unroll
        for (int j = 0; j < F; ++j) {
            float s0 = fmaf(av.x, w4[(ib+0)*F + j], 0.f);
            s0 = fmaf(av.y, w4[(ib+1)*F + j], s0);
            s0 = fmaf(av.z, w4[(ib+2)*F + j], s0);
            s0 = fmaf(av.w, w4[(ib+3)*F + j], s0);
            ev[j] = s0;
        }
#pragma unroll
        for (int j = 0; j < F; ++j) ev[j] += __shfl_xor(ev[j], 1);
#pragma unroll
        for (int j = 0; j < F; ++j) ev[j] += __shfl_xor(ev[j], 2);
#pragma unroll
        for (int j = 0; j < F; ++j) acc[j] += fmaxf(ev[j] + b4s[j], 0.f);
    }
#pragma unroll
    for (int m = 4; m < 64; m <<= 1) {
#pragma unroll
        for (int j = 0; j < F; ++j) acc[j] += __shfl_xor(acc[j], m);
    }

    float fv = 0.f;
    if (valid) {
        int j = l;
        if (j < F) {
            float a = bb[j];
#pragma unroll
            for (int i = 0; i < NIN; ++i)
                a = fmaf(x[(size_t)n * NIN + i], w1[i*F + j], a);
#pragma unroll
            for (int i = 0; i < F; ++i)
                a = fmaf(acc[i], w3[i*F + j], a);
            base[(size_t)n * FP + j] = a;
            fv = fmaxf(a, 0.f);
        } else if (j < FP) {
            base[(size_t)n * FP + j] = 0.f;
        }
    }
    float partner = __shfl_xor(fv, 1);
    if (valid && l < 16 && (l & 1) == 0)
        fb[(size_t)n * 8 + (l >> 1)] = pk_bf16(fv, partner);
}

// ---------- propagation: wave/node, 4 lanes/edge, bf16 L2-resident gather, 2-way unroll
__global__ __launch_bounds__(256) void k_iter(
    const int* __restrict__ srcs, const int* __restrict__ offs,
    const uint2* __restrict__ fbO, const float* __restrict__ base,
    const float* __restrict__ W2,
    unsigned* __restrict__ fbN, float* __restrict__ featN,
    int wfb, int wf32)
{
    __shared__ float w2[F*F];
    __shared__ float sm[4][16];
    int t = threadIdx.x;
    if (t < F*F) w2[t] = W2[t];
    __syncthreads();

    int wid = t >> 6, l = t & 63;
    int n = blockIdx.x * 4 + wid;
    bool valid = n < NN;
    int p0 = 0, p1 = 0;
    if (valid) { p0 = offs[n]; p1 = offs[n + 1]; }
    int g = l >> 2, sub = l & 3;

    float4 a4 = make_float4(0.f, 0.f, 0.f, 0.f);
    int p = p0 + g;
    for (; p + 16 < p1; p += 32) {
        int s0 = srcs[p], s1 = srcs[p + 16];
        uint2 v0 = fbO[(size_t)s0 * 4 + sub];
        uint2 v1 = fbO[(size_t)s1 * 4 + sub];
        a4.x += bf_lo(v0.x) + bf_lo(v1.x);
        a4.y += bf_hi(v0.x) + bf_hi(v1.x);
        a4.z += bf_lo(v0.y) + bf_lo(v1.y);
        a4.w += bf_hi(v0.y) + bf_hi(v1.y);
    }
    if (p < p1) {
        int s0 = srcs[p];
        uint2 v0 = fbO[(size_t)s0 * 4 + sub];
        a4.x += bf_lo(v0.x); a4.y += bf_hi(v0.x);
        a4.z += bf_lo(v0.y); a4.w += bf_hi(v0.y);
    }
#pragma unroll
    for (int m = 4; m < 64; m <<= 1) {
        a4.x += __shfl_xor(a4.x, m); a4.y += __shfl_xor(a4.y, m);
        a4.z += __shfl_xor(a4.z, m); a4.w += __shfl_xor(a4.w, m);
    }
    if (valid && l < 4) {
        uint2 sv = fbO[(size_t)n * 4 + l];
        sm[wid][l*4+0] = a4.x + bf_lo(sv.x); sm[wid][l*4+1] = a4.y + bf_hi(sv.x);
        sm[wid][l*4+2] = a4.z + bf_lo(sv.y); sm[wid][l*4+3] = a4.w + bf_hi(sv.y);
    }
    __syncthreads();
    float fv = 0.f;
    if (valid && l < F) {
        float a = base[(size_t)n * FP + l];
#pragma unroll
        for (int i = 0; i < F; ++i)
            a = fmaf(sm[wid][i], w2[i*F + l], a);
        fv = fmaxf(a, 0.f);
    }
    float partner = __shfl_xor(fv, 1);
    if (valid) {
        if (wfb && l < 16 && (l & 1) == 0)
            fbN[(size_t)n * 8 + (l >> 1)] = pk_bf16(fv, partner);
        if (wf32) {
            if (l < F) featN[(size_t)n * FP + l] = fv;
            else if (l < FP) featN[(size_t)n * FP + l] = 0.f;
        }
    }
}

// ---------- colsum stage 1
__global__ __launch_bounds__(256) void k_colsum(
    const float* __restrict__ feat, float* __restrict__ cpart)
{
    __shared__ float sm[4][F];
    int t = threadIdx.x;
    float v[F];
#pragma unroll
    for (int j = 0; j < F; ++j) v[j] = 0.f;
    for (int n = blockIdx.x * 256 + t; n < NN; n += CSB * 256) {
        const float4* p = (const float4*)(feat + (size_t)n * FP);
        float4 v0 = p[0], v1 = p[1], v2 = p[2];
        v[0]+=v0.x; v[1]+=v0.y; v[2]+=v0.z; v[3]+=v0.w;
        v[4]+=v1.x; v[5]+=v1.y; v[6]+=v1.z; v[7]+=v1.w;
        v[8]+=v2.x; v[9]+=v2.y;
    }
#pragma unroll
    for (int off = 32; off > 0; off >>= 1) {
#pragma unroll
        for (int j = 0; j < F; ++j) v[j] += __shfl_down(v[j], off);
    }
    int wid = t >> 6;
    if ((t & 63) == 0) {
#pragma unroll
        for (int j = 0; j < F; ++j) sm[wid][j] = v[j];
    }
    __syncthreads();
    if (t < F) {
        float s = sm[0][t] + sm[1][t] + sm[2][t] + sm[3][t];
        cpart[blockIdx.x * F + t] = s;
    }
}

// ---------- tiny global-term finisher
__global__ void k_gsmall(
    const float* __restrict__ cpart, const float* __restrict__ W6,
    const float* __restrict__ b6, const float* __restrict__ W5,
    const float* __restrict__ b5, float* __restrict__ gpart)
{
    __shared__ float gcol[F], r1[F];
    int t = threadIdx.x;
    if (t < F) {
        float s = 0.f;
        for (int b = 0; b < CSB; ++b) s += cpart[b * F + t];
        gcol[t] = s;
    }
    __syncthreads();
    if (t < F) {
        float acc = b6[t];
        for (int i = 0; i < F; ++i) acc = fmaf(gcol[i], W6[i*F + t], acc);
        r1[t] = acc > 0.f ? acc : 0.f;
    }
    __syncthreads();
    if (t < OC) {
        float acc = b5[t];
        for (int i = 0; i < F; ++i) acc = fmaf(r1[i], W5[i*OC + t], acc);
        gpart[t] = acc;
    }
}

// ---------- output
__global__ __launch_bounds__(256) void k_out(
    const float* __restrict__ feat, const float* __restrict__ W7,
    const float* __restrict__ b7, const float* __restrict__ W5,
    const float* __restrict__ gpart, float* __restrict__ out)
{
    __shared__ float w7[F*F], bb7[F], w5[F*OC], gp[OC];
    int t = threadIdx.x;
    if (t < F*F) w7[t] = W7[t];
    if (t < F) bb7[t] = b7[t];
    for (int i = t; i < F*OC; i += 256) w5[i] = W5[F*OC + i];
    if (t < OC) gp[t] = gpart[t];
    __syncthreads();
    int n = blockIdx.x * 256 + t;
    if (n >= NN) return;
    const float4* p = (const float4*)(feat + (size_t)n * FP);
    float4 v0 = p[0], v1 = p[1], v2 = p[2];
    float f[F] = {v0.x,v0.y,v0.z,v0.w, v1.x,v1.y,v1.z,v1.w, v2.x,v2.y};
    float h[F];
#pragma unroll
    for (int j = 0; j < F; ++j) h[j] = bb7[j];
#pragma unroll
    for (int i = 0; i < F; ++i) {
        float fi = f[i];
#pragma unroll
        for (int j = 0; j < F; ++j) h[j] = fmaf(fi, w7[i*F + j], h[j]);
    }
#pragma unroll
    for (int j = 0; j < F; ++j) h[j] = h[j] > 0.f ? h[j] : 0.f;
    float o[OC];
#pragma unroll
    for (int k = 0; k < OC; ++k) o[k] = gp[k];
#pragma unroll
    for (int j = 0; j < F; ++j) {
        float hj = h[j];
#pragma unroll
        for (int k = 0; k < OC; ++k) o[k] = fmaf(hj, w5[j*OC + k], o[k]);
    }
    float4* po = (float4*)(out + (size_t)n * OC);
#pragma unroll
    for (int k = 0; k < 8; ++k)
        po[k] = make_float4(o[4*k], o[4*k+1], o[4*k+2], o[4*k+3]);
}

extern "C" void kernel_launch(void* const* d_in, const int* in_sizes, int n_in,
                              void* d_out, int out_size, void* d_ws, size_t ws_size,
                              hipStream_t stream)
{
    const float* x   = (const float*)d_in[0];
    const int*   ei  = (const int*)d_in[1];
    const float* ea  = (const float*)d_in[2];
    const float* W1  = (const float*)d_in[3];
    const float* b1  = (const float*)d_in[4];
    const float* W2  = (const float*)d_in[5];
    const float* b2  = (const float*)d_in[6];
    const float* W3  = (const float*)d_in[7];
    const float* b3  = (const float*)d_in[8];
    const float* W4  = (const float*)d_in[9];
    const float* b4  = (const float*)d_in[10];
    const float* W5  = (const float*)d_in[11];
    const float* b5  = (const float*)d_in[12];
    const float* W6  = (const float*)d_in[13];
    const float* b6  = (const float*)d_in[14];
    const float* W7  = (const float*)d_in[15];
    const float* b7  = (const float*)d_in[16];

    const int* src = ei;            // edge_index[0]
    const int* dst = ei + NE;       // edge_index[1]

    // workspace layout (16B-aligned chunks)
    char* w = (char*)d_ws;
    int2* pair   = (int2*)w;                   w += (size_t)NBK * CAP * 8; // 32.0 MB strided tmp
    int* srcs    = (int*)w;                    w += (size_t)NE * 4;        // 12.8 MB
    int* eids    = (int*)w;                    w += (size_t)NE * 4;
    float* base  = (float*)w;                  w += (size_t)NN * FP * 4;   // 6.4 MB
    float* featA = (float*)w;                  w += (size_t)NN * FP * 4;
    unsigned* fbA = (unsigned*)w;              w += (size_t)NN * 32;       // 3.2 MB
    unsigned* fbB = (unsigned*)w;              w += (size_t)NN * 32;
    int* offs    = (int*)w;                    w += (size_t)(NN + 16) * 4;
    int* cur     = (int*)w;                    w += (size_t)NBK * 4;       // zeroed (counts)
    int* bkbase  = (int*)w;                    w += (size_t)(NBK + 16) * 4;
    float* cpart = (float*)w;                  w += (size_t)CSB * F * 4;
    float* gpart = (float*)w;                  w += 32 * 4;

    const int NB = (NN + 255) / 256;           // 391
    const int WB = (NN + 3) / 4;               // 25000
    const int SB = (NE + CH - 1) / CH;         // 391

    hipMemsetAsync(cur, 0, (size_t)NBK * 4, stream);

    k_binscat<<<SB, 256, 0, stream>>>(src, dst, cur, pair);
    k_bkscan <<<1, 1024, 0, stream>>>(cur, bkbase, offs);
    k_lsort  <<<NBK, 256, 0, stream>>>(bkbase, pair, offs, srcs, eids);

    k_init   <<<WB, 256, 0, stream>>>(x, ea, eids, offs, W1, b1, b2, W3, b3,
                                      W4, b4, base, fbA);

    k_iter   <<<WB, 256, 0, stream>>>(srcs, offs, (const uint2*)fbA, base, W2,
                                      fbB, (float*)nullptr, 1, 0);
    k_iter   <<<WB, 256, 0, stream>>>(srcs, offs, (const uint2*)fbB, base, W2,
                                      (unsigned*)nullptr, featA, 0, 1);

    k_colsum <<<CSB, 256, 0, stream>>>(featA, cpart);
    k_gsmall <<<1, 64, 0, stream>>>(cpart, W6, b6, W5, b5, gpart);
    k_out    <<<NB, 256, 0, stream>>>(featA, W7, b7, W5, gpart, (float*)d_out);
}

// Round 14
// 425.912 us; speedup vs baseline: 2.0000x; 1.0211x over previous
//
#include <hip/hip_runtime.h>

#define NN 100000
#define NE 3200000
#define NIN 16
#define ECH 16
#define F 10
#define FP 16          // padded node row stride = 64 B (base only)
#define OC 32
#define CSB 104        // colsum stage-1 blocks
#define BKSH 7         // 128 nodes per bucket
#define NBK 782        // ceil(NN / 128)
#define CH 8192        // edges per binscat block
#define NIT 32         // CH/256
#define CAP 5120       // fixed tmp capacity per bucket (mean 4096, +16 sigma)

__device__ __forceinline__ unsigned pk_bf16(float a, float b) {
    unsigned ua = __float_as_uint(a); ua = (ua + 0x7FFFu + ((ua >> 16) & 1u)) >> 16;
    unsigned ub = __float_as_uint(b); ub = (ub + 0x7FFFu + ((ub >> 16) & 1u)) >> 16;
    return ua | (ub << 16);
}
__device__ __forceinline__ float bf_lo(unsigned u) { return __uint_as_float(u << 16); }
__device__ __forceinline__ float bf_hi(unsigned u) { return __uint_as_float(u & 0xFFFF0000u); }

// ---------- bin scatter into fixed-capacity strided tmp (dst cached in registers)
__global__ __launch_bounds__(256) void k_binscat(
    const int* __restrict__ src, const int* __restrict__ dst,
    int* __restrict__ cur, int2* __restrict__ pair)
{
    __shared__ int lcnt[NBK];
    __shared__ int lbb[NBK];
    int t = threadIdx.x;
    int e0 = blockIdx.x * CH;
    int e1 = e0 + CH; if (e1 > NE) e1 = NE;
    for (int k = t; k < NBK; k += 256) lcnt[k] = 0;
    __syncthreads();
    int dv[NIT];
#pragma unroll
    for (int it = 0; it < NIT; ++it) {
        int e = e0 + t + it * 256;
        dv[it] = (e < e1) ? dst[e] : -1;
        if (dv[it] >= 0) atomicAdd(&lcnt[dv[it] >> BKSH], 1);
    }
    __syncthreads();
    for (int k = t; k < NBK; k += 256) {
        int c = lcnt[k];
        lbb[k] = c ? (k * CAP + atomicAdd(&cur[k], c)) : 0;
        lcnt[k] = 0;
    }
    __syncthreads();
#pragma unroll
    for (int it = 0; it < NIT; ++it) {
        int e = e0 + t + it * 256;
        int d = dv[it];
        if (d >= 0) {
            int bk = d >> BKSH;
            int idx = atomicAdd(&lcnt[bk], 1);
            pair[lbb[bk] + idx] = make_int2(src[e], ((d & 127) << 22) | e);
        }
    }
}

// ---------- scan of bucket counts (cur) -> compact bkbase
__global__ __launch_bounds__(1024) void k_bkscan(const int* __restrict__ cnt,
                                                 int* __restrict__ bkbase,
                                                 int* __restrict__ offs)
{
    __shared__ int wsum[16], wscan[16];
    int t = threadIdx.x;
    int v = (t < NBK) ? cnt[t] : 0;
    int lane = t & 63, w = t >> 6;
    int inc = v;
    for (int d = 1; d < 64; d <<= 1) { int u = __shfl_up(inc, d); if (lane >= d) inc += u; }
    if (lane == 63) wsum[w] = inc;
    __syncthreads();
    if (t < 16) {
        int u = wsum[t];
        for (int d = 1; d < 16; d <<= 1) { int x2 = __shfl_up(u, d); if (t >= d) u += x2; }
        wscan[t] = u;
    }
    __syncthreads();
    int excl = inc - v + (w > 0 ? wscan[w - 1] : 0);
    if (t < NBK) bkbase[t] = excl;
    if (t == 0) { bkbase[NBK] = NE; offs[NN] = NE; }
}

// ---------- per-bucket counting sort: strided tmp -> compact node-sorted CSR
__global__ __launch_bounds__(256) void k_lsort(
    const int* __restrict__ bkbase, const int2* __restrict__ pair,
    int* __restrict__ offs, int* __restrict__ srcs, int* __restrict__ eids)
{
    __shared__ int lcnt[128];
    __shared__ int lcur[128];
    __shared__ int s0tot;
    int t = threadIdx.x;
    int b = blockIdx.x;
    int base = bkbase[b];
    int cnt = bkbase[b + 1] - base;
    const int2* tp = pair + (size_t)b * CAP;
    int n0 = b << BKSH;
    int nodes = NN - n0; if (nodes > 128) nodes = 128;

    if (t < 128) lcnt[t] = 0;
    __syncthreads();
    for (int i = t; i < cnt; i += 256)
        atomicAdd(&lcnt[((unsigned)tp[i].y) >> 22], 1);
    __syncthreads();
    if (t < 128) {
        int v = lcnt[t];
        int lane = t & 63, w = t >> 6;
        int inc = v;
        for (int d = 1; d < 64; d <<= 1) { int u = __shfl_up(inc, d); if (lane >= d) inc += u; }
        if (w == 0 && lane == 63) s0tot = inc;
        __syncthreads();
        int excl = inc - v + (w == 1 ? s0tot : 0);
        lcur[t] = base + excl;
        if (t < nodes) offs[n0 + t] = base + excl;
    } else {
        __syncthreads();
    }
    __syncthreads();
    for (int i = t; i < cnt; i += 256) {
        int2 pr = tp[i];
        int pe = pr.y;
        int pos = atomicAdd(&lcur[((unsigned)pe) >> 22], 1);
        srcs[pos] = pr.x;
        eids[pos] = pe & 0x3FFFFF;
    }
}

// ---------- fused init: wave/node, 4 lanes/edge, 2-way unrolled ea gather
// writes base (f32) and fb (bf16 packed, 32B/node)
__global__ __launch_bounds__(256) void k_init(
    const float* __restrict__ x, const float* __restrict__ ea,
    const int* __restrict__ eids, const int* __restrict__ offs,
    const float* __restrict__ W1, const float* __restrict__ b1,
    const float* __restrict__ b2,
    const float* __restrict__ W3, const float* __restrict__ b3,
    const float* __restrict__ W4, const float* __restrict__ b4,
    float* __restrict__ base, unsigned* __restrict__ fb)
{
    __shared__ float w1[NIN*F], w3[F*F], w4[ECH*F], bb[F], b4s[F];
    int t = threadIdx.x;
    if (t < NIN*F) w1[t] = W1[t];
    if (t < F*F)   w3[t] = W3[t];
    if (t < ECH*F) w4[t] = W4[t];
    if (t < F) { bb[t] = b1[t] + b2[t] + b3[t]; b4s[t] = b4[t]; }
    __syncthreads();

    int wid = t >> 6, l = t & 63;
    int n = blockIdx.x * 4 + wid;
    bool valid = n < NN;
    int p0 = 0, p1 = 0;
    if (valid) { p0 = offs[n]; p1 = offs[n + 1]; }
    int g = l >> 2, sub = l & 3;
    int ib = sub * 4;

    float acc[F];
#pragma unroll
    for (int j = 0; j < F; ++j) acc[j] = 0.f;

    int p = p0 + g;
    for (; p + 16 < p1; p += 32) {
        int e0 = eids[p], e1 = eids[p + 16];
        float4 av0 = ((const float4*)(ea + (size_t)e0 * ECH))[sub];
        float4 av1 = ((const float4*)(ea + (size_t)e1 * ECH))[sub];
        float ev0[F], ev1[F];
#pragma unroll
        for (int j = 0; j < F; ++j) {
            float s0 = fmaf(av0.x, w4[(ib+0)*F + j], 0.f);
            s0 = fmaf(av0.y, w4[(ib+1)*F + j], s0);
            s0 = fmaf(av0.z, w4[(ib+2)*F + j], s0);
            s0 = fmaf(av0.w, w4[(ib+3)*F + j], s0);
            ev0[j] = s0;
            float s1 = fmaf(av1.x, w4[(ib+0)*F + j], 0.f);
            s1 = fmaf(av1.y, w4[(ib+1)*F + j], s1);
            s1 = fmaf(av1.z, w4[(ib+2)*F + j], s1);
            s1 = fmaf(av1.w, w4[(ib+3)*F + j], s1);
            ev1[j] = s1;
        }
#pragma unroll
        for (int j = 0; j < F; ++j) { ev0[j] += __shfl_xor(ev0[j], 1); ev1[j] += __shfl_xor(ev1[j], 1); }
#pragma unroll
        for (int j = 0; j < F; ++j) { ev0[j] += __shfl_xor(ev0[j], 2); ev1[j] += __shfl_xor(ev1[j], 2); }
#pragma unroll
        for (int j = 0; j < F; ++j)
            acc[j] += fmaxf(ev0[j] + b4s[j], 0.f) + fmaxf(ev1[j] + b4s[j], 0.f);
    }
    if (p < p1) {
        int e0 = eids[p];
        float4 av = ((const float4*)(ea + (size_t)e0 * ECH))[sub];
        float ev[F];
#pragma unroll
        for (int j = 0; j < F; ++j) {
            float s0 = fmaf(av.x, w4[(ib+0)*F + j], 0.f);
            s0 = fmaf(av.y, w4[(ib+1)*F + j], s0);
            s0 = fmaf(av.z, w4[(ib+2)*F + j], s0);
            s0 = fmaf(av.w, w4[(ib+3)*F + j], s0);
            ev[j] = s0;
        }
#pragma unroll
        for (int j = 0; j < F; ++j) ev[j] += __shfl_xor(ev[j], 1);
#pragma unroll
        for (int j = 0; j < F; ++j) ev[j] += __shfl_xor(ev[j], 2);
#pragma unroll
        for (int j = 0; j < F; ++j) acc[j] += fmaxf(ev[j] + b4s[j], 0.f);
    }
#pragma unroll
    for (int m = 4; m < 64; m <<= 1) {
#pragma unroll
        for (int j = 0; j < F; ++j) acc[j] += __shfl_xor(acc[j], m);
    }

    float fv = 0.f;
    if (valid) {
        int j = l;
        if (j < F) {
            float a = bb[j];
#pragma unroll
            for (int i = 0; i < NIN; ++i)
                a = fmaf(x[(size_t)n * NIN + i], w1[i*F + j], a);
#pragma unroll
            for (int i = 0; i < F; ++i)
                a = fmaf(acc[i], w3[i*F + j], a);
            base[(size_t)n * FP + j] = a;
            fv = fmaxf(a, 0.f);
        } else if (j < FP) {
            base[(size_t)n * FP + j] = 0.f;
        }
    }
    float partner = __shfl_xor(fv, 1);
    if (valid && l < 16 && (l & 1) == 0)
        fb[(size_t)n * 8 + (l >> 1)] = pk_bf16(fv, partner);
}

// ---------- propagation: wave/node, 4 lanes/edge, bf16 L2-resident gather
__global__ __launch_bounds__(256) void k_iter(
    const int* __restrict__ srcs, const int* __restrict__ offs,
    const uint2* __restrict__ fbO, const float* __restrict__ base,
    const float* __restrict__ W2, unsigned* __restrict__ fbN)
{
    __shared__ float w2[F*F];
    __shared__ float sm[4][16];
    int t = threadIdx.x;
    if (t < F*F) w2[t] = W2[t];
    __syncthreads();

    int wid = t >> 6, l = t & 63;
    int n = blockIdx.x * 4 + wid;
    bool valid = n < NN;
    int p0 = 0, p1 = 0;
    if (valid) { p0 = offs[n]; p1 = offs[n + 1]; }
    int g = l >> 2, sub = l & 3;

    float4 a4 = make_float4(0.f, 0.f, 0.f, 0.f);
    int p = p0 + g;
    for (; p + 16 < p1; p += 32) {
        int s0 = srcs[p], s1 = srcs[p + 16];
        uint2 v0 = fbO[(size_t)s0 * 4 + sub];
        uint2 v1 = fbO[(size_t)s1 * 4 + sub];
        a4.x += bf_lo(v0.x) + bf_lo(v1.x);
        a4.y += bf_hi(v0.x) + bf_hi(v1.x);
        a4.z += bf_lo(v0.y) + bf_lo(v1.y);
        a4.w += bf_hi(v0.y) + bf_hi(v1.y);
    }
    if (p < p1) {
        int s0 = srcs[p];
        uint2 v0 = fbO[(size_t)s0 * 4 + sub];
        a4.x += bf_lo(v0.x); a4.y += bf_hi(v0.x);
        a4.z += bf_lo(v0.y); a4.w += bf_hi(v0.y);
    }
#pragma unroll
    for (int m = 4; m < 64; m <<= 1) {
        a4.x += __shfl_xor(a4.x, m); a4.y += __shfl_xor(a4.y, m);
        a4.z += __shfl_xor(a4.z, m); a4.w += __shfl_xor(a4.w, m);
    }
    if (valid && l < 4) {
        uint2 sv = fbO[(size_t)n * 4 + l];
        sm[wid][l*4+0] = a4.x + bf_lo(sv.x); sm[wid][l*4+1] = a4.y + bf_hi(sv.x);
        sm[wid][l*4+2] = a4.z + bf_lo(sv.y); sm[wid][l*4+3] = a4.w + bf_hi(sv.y);
    }
    __syncthreads();
    float fv = 0.f;
    if (valid && l < F) {
        float a = base[(size_t)n * FP + l];
#pragma unroll
        for (int i = 0; i < F; ++i)
            a = fmaf(sm[wid][i], w2[i*F + l], a);
        fv = fmaxf(a, 0.f);
    }
    float partner = __shfl_xor(fv, 1);
    if (valid && l < 16 && (l & 1) == 0)
        fbN[(size_t)n * 8 + (l >> 1)] = pk_bf16(fv, partner);
}

// ---------- colsum stage 1 (reads bf16 fb)
__global__ __launch_bounds__(256) void k_colsum(
    const unsigned* __restrict__ fb, float* __restrict__ cpart)
{
    __shared__ float sm[4][F];
    int t = threadIdx.x;
    float v[F];
#pragma unroll
    for (int j = 0; j < F; ++j) v[j] = 0.f;
    for (int n = blockIdx.x * 256 + t; n < NN; n += CSB * 256) {
        const uint4* p = (const uint4*)(fb + (size_t)n * 8);
        uint4 a = p[0];
        unsigned b = fb[(size_t)n * 8 + 4];
        v[0]+=bf_lo(a.x); v[1]+=bf_hi(a.x);
        v[2]+=bf_lo(a.y); v[3]+=bf_hi(a.y);
        v[4]+=bf_lo(a.z); v[5]+=bf_hi(a.z);
        v[6]+=bf_lo(a.w); v[7]+=bf_hi(a.w);
        v[8]+=bf_lo(b);   v[9]+=bf_hi(b);
    }
#pragma unroll
    for (int off = 32; off > 0; off >>= 1) {
#pragma unroll
        for (int j = 0; j < F; ++j) v[j] += __shfl_down(v[j], off);
    }
    int wid = t >> 6;
    if ((t & 63) == 0) {
#pragma unroll
        for (int j = 0; j < F; ++j) sm[wid][j] = v[j];
    }
    __syncthreads();
    if (t < F) {
        float s = sm[0][t] + sm[1][t] + sm[2][t] + sm[3][t];
        cpart[blockIdx.x * F + t] = s;
    }
}

// ---------- tiny global-term finisher
__global__ void k_gsmall(
    const float* __restrict__ cpart, const float* __restrict__ W6,
    const float* __restrict__ b6, const float* __restrict__ W5,
    const float* __restrict__ b5, float* __restrict__ gpart)
{
    __shared__ float gcol[F], r1[F];
    int t = threadIdx.x;
    if (t < F) {
        float s = 0.f;
        for (int b = 0; b < CSB; ++b) s += cpart[b * F + t];
        gcol[t] = s;
    }
    __syncthreads();
    if (t < F) {
        float acc = b6[t];
        for (int i = 0; i < F; ++i) acc = fmaf(gcol[i], W6[i*F + t], acc);
        r1[t] = acc > 0.f ? acc : 0.f;
    }
    __syncthreads();
    if (t < OC) {
        float acc = b5[t];
        for (int i = 0; i < F; ++i) acc = fmaf(r1[i], W5[i*OC + t], acc);
        gpart[t] = acc;
    }
}

// ---------- output (reads bf16 fb)
__global__ __launch_bounds__(256) void k_out(
    const unsigned* __restrict__ fb, const float* __restrict__ W7,
    const float* __restrict__ b7, const float* __restrict__ W5,
    const float* __restrict__ gpart, float* __restrict__ out)
{
    __shared__ float w7[F*F], bb7[F], w5[F*OC], gp[OC];
    int t = threadIdx.x;
    if (t < F*F) w7[t] = W7[t];
    if (t < F) bb7[t] = b7[t];
    for (int i = t; i < F*OC; i += 256) w5[i] = W5[F*OC + i];
    if (t < OC) gp[t] = gpart[t];
    __syncthreads();
    int n = blockIdx.x * 256 + t;
    if (n >= NN) return;
    const uint4* p = (const uint4*)(fb + (size_t)n * 8);
    uint4 a = p[0];
    unsigned b = fb[(size_t)n * 8 + 4];
    float f[F] = {bf_lo(a.x), bf_hi(a.x), bf_lo(a.y), bf_hi(a.y),
                  bf_lo(a.z), bf_hi(a.z), bf_lo(a.w), bf_hi(a.w),
                  bf_lo(b),   bf_hi(b)};
    float h[F];
#pragma unroll
    for (int j = 0; j < F; ++j) h[j] = bb7[j];
#pragma unroll
    for (int i = 0; i < F; ++i) {
        float fi = f[i];
#pragma unroll
        for (int j = 0; j < F; ++j) h[j] = fmaf(fi, w7[i*F + j], h[j]);
    }
#pragma unroll
    for (int j = 0; j < F; ++j) h[j] = h[j] > 0.f ? h[j] : 0.f;
    float o[OC];
#pragma unroll
    for (int k = 0; k < OC; ++k) o[k] = gp[k];
#pragma unroll
    for (int j = 0; j < F; ++j) {
        float hj = h[j];
#pragma unroll
        for (int k = 0; k < OC; ++k) o[k] = fmaf(hj, w5[j*OC + k], o[k]);
    }
    float4* po = (float4*)(out + (size_t)n * OC);
#pragma unroll
    for (int k = 0; k < 8; ++k)
        po[k] = make_float4(o[4*k], o[4*k+1], o[4*k+2], o[4*k+3]);
}

extern "C" void kernel_launch(void* const* d_in, const int* in_sizes, int n_in,
                              void* d_out, int out_size, void* d_ws, size_t ws_size,
                              hipStream_t stream)
{
    const float* x   = (const float*)d_in[0];
    const int*   ei  = (const int*)d_in[1];
    const float* ea  = (const float*)d_in[2];
    const float* W1  = (const float*)d_in[3];
    const float* b1  = (const float*)d_in[4];
    const float* W2  = (const float*)d_in[5];
    const float* b2  = (const float*)d_in[6];
    const float* W3  = (const float*)d_in[7];
    const float* b3  = (const float*)d_in[8];
    const float* W4  = (const float*)d_in[9];
    const float* b4  = (const float*)d_in[10];
    const float* W5  = (const float*)d_in[11];
    const float* b5  = (const float*)d_in[12];
    const float* W6  = (const float*)d_in[13];
    const float* b6  = (const float*)d_in[14];
    const float* W7  = (const float*)d_in[15];
    const float* b7  = (const float*)d_in[16];

    const int* src = ei;            // edge_index[0]
    const int* dst = ei + NE;       // edge_index[1]

    // workspace layout (16B-aligned chunks)
    char* w = (char*)d_ws;
    int2* pair   = (int2*)w;                   w += (size_t)NBK * CAP * 8; // 32.0 MB strided tmp
    int* srcs    = (int*)w;                    w += (size_t)NE * 4;        // 12.8 MB
    int* eids    = (int*)w;                    w += (size_t)NE * 4;
    float* base  = (float*)w;                  w += (size_t)NN * FP * 4;   // 6.4 MB
    unsigned* fbA = (unsigned*)w;              w += (size_t)NN * 32;       // 3.2 MB
    unsigned* fbB = (unsigned*)w;              w += (size_t)NN * 32;
    int* offs    = (int*)w;                    w += (size_t)(NN + 16) * 4;
    int* cur     = (int*)w;                    w += (size_t)NBK * 4;       // zeroed (counts)
    int* bkbase  = (int*)w;                    w += (size_t)(NBK + 16) * 4;
    float* cpart = (float*)w;                  w += (size_t)CSB * F * 4;
    float* gpart = (float*)w;                  w += 32 * 4;

    const int NB = (NN + 255) / 256;           // 391
    const int WB = (NN + 3) / 4;               // 25000
    const int SB = (NE + CH - 1) / CH;         // 391

    hipMemsetAsync(cur, 0, (size_t)NBK * 4, stream);

    k_binscat<<<SB, 256, 0, stream>>>(src, dst, cur, pair);
    k_bkscan <<<1, 1024, 0, stream>>>(cur, bkbase, offs);
    k_lsort  <<<NBK, 256, 0, stream>>>(bkbase, pair, offs, srcs, eids);

    k_init   <<<WB, 256, 0, stream>>>(x, ea, eids, offs, W1, b1, b2, W3, b3,
                                      W4, b4, base, fbA);

    k_iter   <<<WB, 256, 0, stream>>>(srcs, offs, (const uint2*)fbA, base, W2, fbB);
    k_iter   <<<WB, 256, 0, stream>>>(srcs, offs, (const uint2*)fbB, base, W2, fbA);

    k_colsum <<<CSB, 256, 0, stream>>>(fbA, cpart);
    k_gsmall <<<1, 64, 0, stream>>>(cpart, W6, b6, W5, b5, gpart);
    k_out    <<<NB, 256, 0, stream>>>(fbA, W7, b7, W5, gpart, (float*)d_out);
}